// Round 8
// baseline (740.246 us; speedup 1.0000x reference)
//
#include <hip/hip_runtime.h>
#include <hip/hip_bf16.h>

// MambaMinimalBlock: B=4, L=2048, D_MODEL=1024, D_STATE=16, D_CONV=4,
// D_INNER=2048, BL=8192. fp32 in/out.
//
// GEMMs: bf16 MFMA, weight-split (W = Whi + Wlo), bf16 activations.
// R8: LDS bank-conflict fix — fragment row stride padded 32->36 ushorts
// (72 B = 18 banks; 16 rows x stride-18-words = 16 distinct even banks,
// quad offset +4 words stays even => 2-way aliasing = free per m136).
// 72 B is not 16B-aligned, so all LDS I/O is explicit uint2 pairs (b64).
// R7 counters: SQ_LDS_BANK_CONFLICT=1.26e7 on the dt GEMM (8-way on
// ds_read_b128 fragments), MfmaUtil 40% => LDS-bound, not MFMA-bound.
//
// Scan: d-parallel chunked 2-pass. bc: split-K MFMA + reduce.

typedef float  f32x4  __attribute__((ext_vector_type(4)));
typedef short  bf16x8 __attribute__((ext_vector_type(8)));

#define NCHK 16
#define CLEN 128
#define SW   8      // scan window (double-buffered)
#define LSTR 36     // LDS row stride in ushorts (k=32 data + 4 pad)

__device__ __forceinline__ ushort f2bf(float f) {
    uint u = __float_as_uint(f);
    u += 0x7FFF + ((u >> 16) & 1);          // RNE
    return (ushort)(u >> 16);
}
__device__ __forceinline__ float bf2f(ushort h) {
    return __uint_as_float((uint)h << 16);
}
__device__ __forceinline__ float softplus_f(float x) {
    return fmaxf(x, 0.f) + __logf(1.f + __expf(-fabsf(x)));
}
__device__ __forceinline__ float silu_f(float x) {
    return x / (1.f + __expf(-x));
}

// 8-B-aligned LDS accessors (emit ds_read/write_b64; padded stride breaks
// 16-B alignment so b128 is not legal here).
__device__ __forceinline__ bf16x8 lds_read8(const ushort* p) {
    union { bf16x8 v; uint2 u[2]; } t;
    t.u[0] = *(const uint2*)(p);
    t.u[1] = *(const uint2*)(p + 4);
    return t.v;
}
__device__ __forceinline__ void lds_write8(ushort* p, uint4 v) {
    *(uint2*)(p)     = make_uint2(v.x, v.y);
    *(uint2*)(p + 4) = make_uint2(v.z, v.w);
}

__global__ __launch_bounds__(256)
void split_w_kernel(const float* __restrict__ src, ushort* __restrict__ hi,
                    ushort* __restrict__ lo)
{
    const int i = blockIdx.x * 256 + threadIdx.x;
    float4 v = ((const float4*)src)[i];
    ushort4 h, l;
    h.x = f2bf(v.x); l.x = f2bf(v.x - bf2f(h.x));
    h.y = f2bf(v.y); l.y = f2bf(v.y - bf2f(h.y));
    h.z = f2bf(v.z); l.z = f2bf(v.z - bf2f(h.z));
    h.w = f2bf(v.w); l.w = f2bf(v.w - bf2f(h.w));
    ((ushort4*)hi)[i] = h;
    ((ushort4*)lo)[i] = l;
}

__global__ __launch_bounds__(256)
void cvt_bf16_kernel(const float* __restrict__ src, ushort* __restrict__ dst)
{
    const int i = blockIdx.x * 256 + threadIdx.x;
    float4 v = ((const float4*)src)[i];
    ushort4 h;
    h.x = f2bf(v.x); h.y = f2bf(v.y); h.z = f2bf(v.z); h.w = f2bf(v.w);
    ((ushort4*)dst)[i] = h;
}

// C[M,N] = A[M,K](bf16) * (Bh+Bl)[N,K]^T (bf16 planes), fp32 accumulate.
// EPI: 0 = fp32 store, 1 = softplus(v + bias[col]) fp32, 2 = bf16 store.
template <int EPI>
__global__ __launch_bounds__(256)
void gemm_mfma(const ushort* __restrict__ A, const ushort* __restrict__ Bh,
               const ushort* __restrict__ Bl, const float* __restrict__ bias,
               void* __restrict__ Cout, int N, int K)
{
    __shared__ ushort As[128 * LSTR];    // 9 KB each, 27 KB total
    __shared__ ushort Bhs[128 * LSTR];
    __shared__ ushort Bls[128 * LSTR];

    const int tid  = threadIdx.x;
    const int lane = tid & 63;
    const int wave = tid >> 6;
    const int wm   = (wave >> 1) * 64;
    const int wn   = (wave & 1) * 64;
    const int row0 = blockIdx.y * 128;
    const int col0 = blockIdx.x * 128;

    const int crow   = tid >> 2;          // 0..63
    const int cpiece = (tid & 3) * 8;     // ushort offset within row
    const ushort* Ag0 = A  + (size_t)(row0 + crow) * K + cpiece;
    const ushort* Ag1 = A  + (size_t)(row0 + crow + 64) * K + cpiece;
    const ushort* Bg0 = Bh + (size_t)(col0 + crow) * K + cpiece;
    const ushort* Bg1 = Bh + (size_t)(col0 + crow + 64) * K + cpiece;
    const ushort* Cg0 = Bl + (size_t)(col0 + crow) * K + cpiece;
    const ushort* Cg1 = Bl + (size_t)(col0 + crow + 64) * K + cpiece;
    const int st0 = crow * LSTR + cpiece;
    const int st1 = (crow + 64) * LSTR + cpiece;

    const int fq  = (lane >> 4) * 8;
    const int fra = (wm + (lane & 15)) * LSTR + fq;
    const int frb = (wn + (lane & 15)) * LSTR + fq;

    f32x4 acc[4][4];
#pragma unroll
    for (int mi = 0; mi < 4; ++mi)
#pragma unroll
        for (int ni = 0; ni < 4; ++ni)
            acc[mi][ni] = (f32x4){0.f, 0.f, 0.f, 0.f};

    uint4 ra0 = *(const uint4*)Ag0, ra1 = *(const uint4*)Ag1;
    uint4 rh0 = *(const uint4*)Bg0, rh1 = *(const uint4*)Bg1;
    uint4 rl0 = *(const uint4*)Cg0, rl1 = *(const uint4*)Cg1;

    for (int k0 = 0; k0 < K; k0 += 32) {
        __syncthreads();
        lds_write8(As  + st0, ra0);
        lds_write8(As  + st1, ra1);
        lds_write8(Bhs + st0, rh0);
        lds_write8(Bhs + st1, rh1);
        lds_write8(Bls + st0, rl0);
        lds_write8(Bls + st1, rl1);
        __syncthreads();
        if (k0 + 32 < K) {
            ra0 = *(const uint4*)(Ag0 + k0 + 32);
            ra1 = *(const uint4*)(Ag1 + k0 + 32);
            rh0 = *(const uint4*)(Bg0 + k0 + 32);
            rh1 = *(const uint4*)(Bg1 + k0 + 32);
            rl0 = *(const uint4*)(Cg0 + k0 + 32);
            rl1 = *(const uint4*)(Cg1 + k0 + 32);
        }
        bf16x8 af[4], bh[4], bl[4];
#pragma unroll
        for (int mi = 0; mi < 4; ++mi)
            af[mi] = lds_read8(As + fra + mi * 16 * LSTR);
#pragma unroll
        for (int ni = 0; ni < 4; ++ni) {
            bh[ni] = lds_read8(Bhs + frb + ni * 16 * LSTR);
            bl[ni] = lds_read8(Bls + frb + ni * 16 * LSTR);
        }
#pragma unroll
        for (int mi = 0; mi < 4; ++mi)
#pragma unroll
            for (int ni = 0; ni < 4; ++ni) {
                acc[mi][ni] = __builtin_amdgcn_mfma_f32_16x16x32_bf16(
                    af[mi], bh[ni], acc[mi][ni], 0, 0, 0);
                acc[mi][ni] = __builtin_amdgcn_mfma_f32_16x16x32_bf16(
                    af[mi], bl[ni], acc[mi][ni], 0, 0, 0);
            }
    }

#pragma unroll
    for (int mi = 0; mi < 4; ++mi) {
        const int rg = row0 + wm + mi * 16 + (lane >> 4) * 4;
#pragma unroll
        for (int ni = 0; ni < 4; ++ni) {
            const int cg = col0 + wn + ni * 16 + (lane & 15);
            f32x4 v = acc[mi][ni];
            if (EPI == 1) {
                const float bv = bias[cg];
#pragma unroll
                for (int r = 0; r < 4; ++r) v[r] = softplus_f(v[r] + bv);
            }
#pragma unroll
            for (int r = 0; r < 4; ++r) {
                if (EPI == 2)
                    ((ushort*)Cout)[(size_t)(rg + r) * N + cg] = f2bf(v[r]);
                else
                    ((float*)Cout)[(size_t)(rg + r) * N + cg] = v[r];
            }
        }
    }
}

// Split-K bc GEMM: part[ks] = xc[:, ks*256:(ks+1)*256] @ Wx^T slice.
// M=8192, N=32, K-slice=256. Grid (8, 64). Padded-LDS variant.
__global__ __launch_bounds__(256)
void gemm_bc_mfma(const ushort* __restrict__ A, const ushort* __restrict__ Bh,
                  const ushort* __restrict__ Bl, float* __restrict__ part)
{
    __shared__ ushort As[128 * LSTR];
    __shared__ ushort Bhs[32 * LSTR];
    __shared__ ushort Bls[32 * LSTR];

    const int tid  = threadIdx.x;
    const int lane = tid & 63;
    const int wave = tid >> 6;
    const int ks   = blockIdx.x;     // 0..7
    const int mb   = blockIdx.y;     // 0..63
    const int row0 = mb * 128;
    const int kb   = ks * 256;

    const int crow   = tid >> 2;
    const int cpiece = (tid & 3) * 8;
    const ushort* Ag0 = A + (size_t)(row0 + crow) * 2048 + kb + cpiece;
    const ushort* Ag1 = A + (size_t)(row0 + crow + 64) * 2048 + kb + cpiece;
    const int st0 = crow * LSTR + cpiece;
    const int st1 = (crow + 64) * LSTR + cpiece;

    const int t2     = tid & 127;
    const int brow   = t2 >> 2;      // 0..31
    const int bpiece = (t2 & 3) * 8;
    const ushort* Bg = (tid < 128 ? Bh : Bl) + (size_t)brow * 2048 + kb + bpiece;
    ushort* Bdst     = (tid < 128 ? Bhs : Bls) + brow * LSTR + bpiece;

    const int fq  = (lane >> 4) * 8;
    const int wm  = wave * 32;
    const int fra = (wm + (lane & 15)) * LSTR + fq;
    const int frb = (lane & 15) * LSTR + fq;

    f32x4 acc[2][2];
#pragma unroll
    for (int mi = 0; mi < 2; ++mi)
#pragma unroll
        for (int ni = 0; ni < 2; ++ni)
            acc[mi][ni] = (f32x4){0.f, 0.f, 0.f, 0.f};

    uint4 ra0 = *(const uint4*)Ag0, ra1 = *(const uint4*)Ag1;
    uint4 rb  = *(const uint4*)Bg;

    for (int kt = 0; kt < 8; ++kt) {
        __syncthreads();
        lds_write8(As + st0, ra0);
        lds_write8(As + st1, ra1);
        lds_write8(Bdst, rb);
        __syncthreads();
        if (kt < 7) {
            ra0 = *(const uint4*)(Ag0 + (kt + 1) * 32);
            ra1 = *(const uint4*)(Ag1 + (kt + 1) * 32);
            rb  = *(const uint4*)(Bg + (kt + 1) * 32);
        }
        bf16x8 af[2], bhf[2], blf[2];
#pragma unroll
        for (int mi = 0; mi < 2; ++mi)
            af[mi] = lds_read8(As + fra + mi * 16 * LSTR);
#pragma unroll
        for (int ni = 0; ni < 2; ++ni) {
            bhf[ni] = lds_read8(Bhs + frb + ni * 16 * LSTR);
            blf[ni] = lds_read8(Bls + frb + ni * 16 * LSTR);
        }
#pragma unroll
        for (int mi = 0; mi < 2; ++mi)
#pragma unroll
            for (int ni = 0; ni < 2; ++ni) {
                acc[mi][ni] = __builtin_amdgcn_mfma_f32_16x16x32_bf16(
                    af[mi], bhf[ni], acc[mi][ni], 0, 0, 0);
                acc[mi][ni] = __builtin_amdgcn_mfma_f32_16x16x32_bf16(
                    af[mi], blf[ni], acc[mi][ni], 0, 0, 0);
            }
    }

#pragma unroll
    for (int mi = 0; mi < 2; ++mi) {
        const int rg = row0 + wm + mi * 16 + (lane >> 4) * 4;
#pragma unroll
        for (int ni = 0; ni < 2; ++ni) {
            const int cg = ni * 16 + (lane & 15);
            f32x4 v = acc[mi][ni];
#pragma unroll
            for (int r = 0; r < 4; ++r)
                part[((size_t)ks * 8192 + rg + r) * 32 + cg] = v[r];
        }
    }
}

__global__ __launch_bounds__(256)
void bc_reduce_kernel(const float* __restrict__ part, float* __restrict__ bc)
{
    const int i = blockIdx.x * 256 + threadIdx.x;   // 262144
    float s = 0.f;
#pragma unroll
    for (int ks = 0; ks < 8; ++ks)
        s += part[(size_t)ks * 262144 + i];
    bc[i] = s;
}

// Depthwise causal conv1d (4 taps) + bias + silu; bf16 in, bf16 out.
__global__ __launch_bounds__(256)
void conv_silu_kernel(const ushort* __restrict__ xi, const float* __restrict__ cw,
                      const float* __restrict__ cb, ushort* __restrict__ xc)
{
    const int idx = blockIdx.x * 256 + threadIdx.x;
    const int e   = (idx & 511) << 2;
    const int row = idx >> 9;
    const int l   = row & 2047;

    const float4 w0 = *(const float4*)(cw + (size_t)(e + 0) * 4);
    const float4 w1 = *(const float4*)(cw + (size_t)(e + 1) * 4);
    const float4 w2 = *(const float4*)(cw + (size_t)(e + 2) * 4);
    const float4 w3 = *(const float4*)(cw + (size_t)(e + 3) * 4);

    float4 acc = *(const float4*)(cb + e);

#define CONV_TAP(K_, WSEL)                                                  \
    {                                                                       \
        ushort4 t = *(const ushort4*)(xi + (size_t)(row - (K_)) * 2048 + e);\
        acc.x = fmaf(bf2f(t.x), w0.WSEL, acc.x);                            \
        acc.y = fmaf(bf2f(t.y), w1.WSEL, acc.y);                            \
        acc.z = fmaf(bf2f(t.z), w2.WSEL, acc.z);                            \
        acc.w = fmaf(bf2f(t.w), w3.WSEL, acc.w);                            \
    }
    if (l >= 3) CONV_TAP(3, x)
    if (l >= 2) CONV_TAP(2, y)
    if (l >= 1) CONV_TAP(1, z)
    CONV_TAP(0, w)
#undef CONV_TAP

    ushort4 o;
    o.x = f2bf(silu_f(acc.x)); o.y = f2bf(silu_f(acc.y));
    o.z = f2bf(silu_f(acc.z)); o.w = f2bf(silu_f(acc.w));
    *(ushort4*)(xc + (size_t)row * 2048 + e) = o;
}

// ---- d-parallel chunked selective scan ----

// Pass 1: chunks 0..NCHK-2, h from 0, writes he + P = exp(A * sum dt).
__global__ __launch_bounds__(256)
void scan_part1(const ushort* __restrict__ xcb, const float* __restrict__ dbuf,
                const float* __restrict__ bcbuf, const float* __restrict__ A_log,
                float* __restrict__ sum_h, float* __restrict__ sum_p)
{
    const int c    = blockIdx.x >> 5;          // 0..14
    const int b    = (blockIdx.x >> 3) & 3;
    const int dblk = blockIdx.x & 7;
    const int d    = dblk * 256 + threadIdx.x;

    float Aval[16];
#pragma unroll
    for (int q = 0; q < 4; ++q) {
        float4 al = *(const float4*)(A_log + (size_t)d * 16 + q * 4);
        Aval[q*4+0] = -__expf(al.x); Aval[q*4+1] = -__expf(al.y);
        Aval[q*4+2] = -__expf(al.z); Aval[q*4+3] = -__expf(al.w);
    }

    const size_t row0 = (size_t)b * 2048 + (size_t)c * CLEN;
    const float*  dp  = dbuf + row0 * 2048 + d;
    const ushort* xp  = xcb  + row0 * 2048 + d;
    const float*  bcp = bcbuf + row0 * 32;

    float h[16];
#pragma unroll
    for (int s = 0; s < 16; ++s) h[s] = 0.f;
    float S = 0.f;

    float wdt[SW], wxv[SW];
#pragma unroll
    for (int j = 0; j < SW; ++j) {
        wdt[j] = dp[(size_t)j * 2048];
        wxv[j] = bf2f(xp[(size_t)j * 2048]);
    }
    float curB[16];
#pragma unroll
    for (int q = 0; q < 4; ++q)
        *(float4*)&curB[q*4] = *(const float4*)(bcp + q * 4);

    for (int l0 = 0; l0 < CLEN; l0 += SW) {
        float ndt[SW], nxv[SW];
        const bool more = (l0 + SW) < CLEN;
        if (more) {
#pragma unroll
            for (int j = 0; j < SW; ++j) {
                const size_t o = (size_t)(l0 + SW + j);
                ndt[j] = dp[o * 2048];
                nxv[j] = bf2f(xp[o * 2048]);
            }
        }
#pragma unroll
        for (int j = 0; j < SW; ++j) {
            const int l = l0 + j;
            float nB[16];
            if (l + 1 < CLEN) {
#pragma unroll
                for (int q = 0; q < 4; ++q)
                    *(float4*)&nB[q*4] = *(const float4*)(bcp + (size_t)(l+1) * 32 + q * 4);
            }
            const float dt = wdt[j];
            const float t  = dt * wxv[j];
            S += dt;
#pragma unroll
            for (int s = 0; s < 16; ++s)
                h[s] = __expf(dt * Aval[s]) * h[s] + curB[s] * t;
            if (l + 1 < CLEN) {
#pragma unroll
                for (int s = 0; s < 16; ++s) curB[s] = nB[s];
            }
        }
        if (more) {
#pragma unroll
            for (int j = 0; j < SW; ++j) { wdt[j] = ndt[j]; wxv[j] = nxv[j]; }
        }
    }

    float* sh = sum_h + ((((size_t)c * 4 + b) * 2048 + d) << 4);
    float* sp = sum_p + ((((size_t)c * 4 + b) * 2048 + d) << 4);
#pragma unroll
    for (int q = 0; q < 4; ++q) {
        *(float4*)(sh + q * 4) = make_float4(h[q*4], h[q*4+1], h[q*4+2], h[q*4+3]);
        *(float4*)(sp + q * 4) = make_float4(__expf(Aval[q*4] * S), __expf(Aval[q*4+1] * S),
                                             __expf(Aval[q*4+2] * S), __expf(Aval[q*4+3] * S));
    }
}

// Pass 2: all NCHK chunks; fold preceding summaries, scan, y bf16 out.
__global__ __launch_bounds__(256)
void scan_part2(const ushort* __restrict__ zbuf, const ushort* __restrict__ xcb,
                const float* __restrict__ dbuf, const float* __restrict__ bcbuf,
                const float* __restrict__ A_log, const float* __restrict__ Dp,
                const float* __restrict__ sum_h, const float* __restrict__ sum_p,
                ushort* __restrict__ ybuf)
{
    const int c    = blockIdx.x >> 5;          // 0..15
    const int b    = (blockIdx.x >> 3) & 3;
    const int dblk = blockIdx.x & 7;
    const int d    = dblk * 256 + threadIdx.x;

    float Aval[16];
#pragma unroll
    for (int q = 0; q < 4; ++q) {
        float4 al = *(const float4*)(A_log + (size_t)d * 16 + q * 4);
        Aval[q*4+0] = -__expf(al.x); Aval[q*4+1] = -__expf(al.y);
        Aval[q*4+2] = -__expf(al.z); Aval[q*4+3] = -__expf(al.w);
    }
    const float Dv = Dp[d];

    float h[16];
#pragma unroll
    for (int s = 0; s < 16; ++s) h[s] = 0.f;
    for (int j = 0; j < c; ++j) {              // fold chunk summaries
        const float* sh = sum_h + ((((size_t)j * 4 + b) * 2048 + d) << 4);
        const float* sp = sum_p + ((((size_t)j * 4 + b) * 2048 + d) << 4);
#pragma unroll
        for (int q = 0; q < 4; ++q) {
            float4 vh = *(const float4*)(sh + q * 4);
            float4 vp = *(const float4*)(sp + q * 4);
            h[q*4+0] = vh.x + vp.x * h[q*4+0];
            h[q*4+1] = vh.y + vp.y * h[q*4+1];
            h[q*4+2] = vh.z + vp.z * h[q*4+2];
            h[q*4+3] = vh.w + vp.w * h[q*4+3];
        }
    }

    const size_t row0 = (size_t)b * 2048 + (size_t)c * CLEN;
    const float*  dp  = dbuf + row0 * 2048 + d;
    const ushort* xp  = xcb  + row0 * 2048 + d;
    const ushort* zp  = zbuf + row0 * 2048 + d;
    const float*  bcp = bcbuf + row0 * 32;
    ushort*       yp  = ybuf + row0 * 2048 + d;

    float wdt[SW], wxv[SW], wzv[SW];
#pragma unroll
    for (int j = 0; j < SW; ++j) {
        wdt[j] = dp[(size_t)j * 2048];
        wxv[j] = bf2f(xp[(size_t)j * 2048]);
        wzv[j] = bf2f(zp[(size_t)j * 2048]);
    }
    float curB[16], curC[16];
#pragma unroll
    for (int q = 0; q < 4; ++q) {
        *(float4*)&curB[q*4] = *(const float4*)(bcp + q * 4);
        *(float4*)&curC[q*4] = *(const float4*)(bcp + 16 + q * 4);
    }

    for (int l0 = 0; l0 < CLEN; l0 += SW) {
        float ndt[SW], nxv[SW], nzv[SW];
        const bool more = (l0 + SW) < CLEN;
        if (more) {
#pragma unroll
            for (int j = 0; j < SW; ++j) {
                const size_t o = (size_t)(l0 + SW + j);
                ndt[j] = dp[o * 2048];
                nxv[j] = bf2f(xp[o * 2048]);
                nzv[j] = bf2f(zp[o * 2048]);
            }
        }
#pragma unroll
        for (int j = 0; j < SW; ++j) {
            const int l = l0 + j;
            float nB[16], nC[16];
            if (l + 1 < CLEN) {
#pragma unroll
                for (int q = 0; q < 4; ++q) {
                    *(float4*)&nB[q*4] = *(const float4*)(bcp + (size_t)(l+1) * 32 + q * 4);
                    *(float4*)&nC[q*4] = *(const float4*)(bcp + (size_t)(l+1) * 32 + 16 + q * 4);
                }
            }
            const float dt = wdt[j];
            const float t  = dt * wxv[j];
#pragma unroll
            for (int s = 0; s < 16; ++s)
                h[s] = __expf(dt * Aval[s]) * h[s] + curB[s] * t;
            float y0 = 0.f, y1 = 0.f, y2 = 0.f, y3 = 0.f;
#pragma unroll
            for (int s = 0; s < 16; s += 4) {
                y0 = fmaf(h[s+0], curC[s+0], y0);
                y1 = fmaf(h[s+1], curC[s+1], y1);
                y2 = fmaf(h[s+2], curC[s+2], y2);
                y3 = fmaf(h[s+3], curC[s+3], y3);
            }
            float y = (y0 + y1) + (y2 + y3) + Dv * wxv[j];
            yp[(size_t)l * 2048] = f2bf(y * silu_f(wzv[j]));
            if (l + 1 < CLEN) {
#pragma unroll
                for (int s = 0; s < 16; ++s) { curB[s] = nB[s]; curC[s] = nC[s]; }
            }
        }
        if (more) {
#pragma unroll
            for (int j = 0; j < SW; ++j) {
                wdt[j] = ndt[j]; wxv[j] = nxv[j]; wzv[j] = nzv[j];
            }
        }
    }
}

extern "C" void kernel_launch(void* const* d_in, const int* in_sizes, int n_in,
                              void* d_out, int out_size, void* d_ws, size_t ws_size,
                              hipStream_t stream)
{
    const float* x          = (const float*)d_in[0];
    const float* in_proj_w  = (const float*)d_in[1];
    const float* conv_w     = (const float*)d_in[2];
    const float* conv_b     = (const float*)d_in[3];
    const float* x_proj_w   = (const float*)d_in[4];
    const float* dt_proj_w  = (const float*)d_in[5];
    const float* dt_proj_b  = (const float*)d_in[6];
    const float* A_log      = (const float*)d_in[7];
    const float* Dp         = (const float*)d_in[8];
    const float* out_proj_w = (const float*)d_in[9];
    float* out = (float*)d_out;

    ushort* XI    = (ushort*)d_ws;                    // 32 MB; later Y'
    ushort* Z     = XI + 16777216;                    // 32 MB
    ushort* XC2   = Z + 16777216;                     // 32 MB
    float*  DELTA = (float*)(XC2 + 16777216);         // 64 MB
    ushort* XP    = (ushort*)DELTA;                   // x' bf16 (pre-DELTA)
    ushort* WINH  = (ushort*)(DELTA + 16777216);      // 8 MB
    ushort* WINL  = WINH + 4194304;                   // 8 MB
    ushort* WDTH  = WINL + 4194304;                   // 8 MB
    ushort* WDTL  = WDTH + 4194304;                   // 8 MB
    ushort* WOUTH = WDTL + 4194304;                   // 4 MB
    ushort* WOUTL = WOUTH + 2097152;                  // 4 MB
    float*  BC    = (float*)(WOUTL + 2097152);        // 1 MB
    float*  SUMH  = BC + 262144;                      // 8 MB
    float*  SUMP  = SUMH + 2097152;                   // 8 MB
    ushort* XPH   = (ushort*)(SUMP + 2097152);        // 128 KB (x_proj hi)
    ushort* XPL   = XPH + 65536;                      // 128 KB
    float*  PART  = (float*)(XPL + 65536);            // 8 MB split-K partials
    ushort* Yp    = XI;

    const dim3 blk(256);

    // 0) conversions
    cvt_bf16_kernel<<<dim3(8192), blk, 0, stream>>>(x, XP);
    split_w_kernel<<<dim3(4096), blk, 0, stream>>>(in_proj_w, WINH, WINL);
    split_w_kernel<<<dim3(4096), blk, 0, stream>>>(dt_proj_w, WDTH, WDTL);
    split_w_kernel<<<dim3(2048), blk, 0, stream>>>(out_proj_w, WOUTH, WOUTL);
    split_w_kernel<<<dim3(64),   blk, 0, stream>>>(x_proj_w, XPH, XPL);

    // 1) xi, z
    gemm_mfma<2><<<dim3(16, 64), blk, 0, stream>>>(XP, WINH, WINL, nullptr, XI, 2048, 1024);
    gemm_mfma<2><<<dim3(16, 64), blk, 0, stream>>>(XP, WINH + 2097152, WINL + 2097152,
                                                   nullptr, Z, 2048, 1024);

    // 2) xc = silu(conv(xi) + b)
    conv_silu_kernel<<<dim3(16384), blk, 0, stream>>>(XI, conv_w, conv_b, XC2);

    // 3) delta = softplus(xc @ Wdt^T + b)
    gemm_mfma<1><<<dim3(16, 64), blk, 0, stream>>>(XC2, WDTH, WDTL, dt_proj_b, DELTA, 2048, 2048);

    // 4) bc = xc @ x_proj_w^T  (split-K MFMA + reduce)
    gemm_bc_mfma<<<dim3(8, 64), blk, 0, stream>>>(XC2, XPH, XPL, PART);
    bc_reduce_kernel<<<dim3(1024), blk, 0, stream>>>(PART, BC);

    // 5) chunked scan: pass1 (chunks 0..14) then pass2 (all 16)
    scan_part1<<<dim3((NCHK - 1) * 32), blk, 0, stream>>>(XC2, DELTA, BC, A_log, SUMH, SUMP);
    scan_part2<<<dim3(NCHK * 32), blk, 0, stream>>>(Z, XC2, DELTA, BC, A_log, Dp,
                                                    SUMH, SUMP, Yp);

    // 6) out = y @ Wout^T
    gemm_mfma<0><<<dim3(8, 64), blk, 0, stream>>>(Yp, WOUTH, WOUTL, nullptr, out, 1024, 2048);
}

// Round 9
// 643.836 us; speedup vs baseline: 1.1497x; 1.1497x over previous
//
#include <hip/hip_runtime.h>
#include <hip/hip_bf16.h>

// MambaMinimalBlock: B=4, L=2048, D_MODEL=1024, D_STATE=16, D_CONV=4,
// D_INNER=2048, BL=8192. fp32 in/out.
//
// R9: big GEMMs go plain-bf16 (weights + activations, fp32 accumulate).
// R7/R8 showed the weight-split GEMM sits at the m97 structural plateau
// (~850-900 TF executed) regardless of LDS tuning — so halve executed
// FLOPs instead. Error budget: activation-only quant gave 1.465e-3 vs
// 5.586e-3 threshold; adding weight quant (independent, same magnitude)
// predicts ~2.5e-3. bc keeps hi/lo split (B/C feed the scan; cost tiny).
//
// LDS: tiled conflict-free layout — 16B chunk (row,q) stored at ushort
// addr (row>>4)*512 + q*128 + (row&15)*8. Each wave's fragment read and
// each staging write covers one dense contiguous 1KB block => zero bank
// conflicts, full b128. (R7 linear layout: 8-way read conflicts, 1.26e7
// SQ_LDS_BANK_CONFLICT; R8 pad+b64: same conflict cycles, more instrs.)
//
// Scan: d-parallel chunked 2-pass. bc: split-K MFMA + reduce.

typedef float  f32x4  __attribute__((ext_vector_type(4)));
typedef short  bf16x8 __attribute__((ext_vector_type(8)));

#define NCHK 16
#define CLEN 128
#define SW   8      // scan window (double-buffered)

__device__ __forceinline__ ushort f2bf(float f) {
    uint u = __float_as_uint(f);
    u += 0x7FFF + ((u >> 16) & 1);          // RNE
    return (ushort)(u >> 16);
}
__device__ __forceinline__ float bf2f(ushort h) {
    return __uint_as_float((uint)h << 16);
}
__device__ __forceinline__ float softplus_f(float x) {
    return fmaxf(x, 0.f) + __logf(1.f + __expf(-fabsf(x)));
}
__device__ __forceinline__ float silu_f(float x) {
    return x / (1.f + __expf(-x));
}

// tiled LDS chunk address (ushort units): row, q = 16B k-chunk (0..3)
__device__ __forceinline__ int lds_addr(int row, int q) {
    return ((row >> 4) << 9) + (q << 7) + ((row & 15) << 3);
}

__global__ __launch_bounds__(256)
void split_w_kernel(const float* __restrict__ src, ushort* __restrict__ hi,
                    ushort* __restrict__ lo)
{
    const int i = blockIdx.x * 256 + threadIdx.x;
    float4 v = ((const float4*)src)[i];
    ushort4 h, l;
    h.x = f2bf(v.x); l.x = f2bf(v.x - bf2f(h.x));
    h.y = f2bf(v.y); l.y = f2bf(v.y - bf2f(h.y));
    h.z = f2bf(v.z); l.z = f2bf(v.z - bf2f(h.z));
    h.w = f2bf(v.w); l.w = f2bf(v.w - bf2f(h.w));
    ((ushort4*)hi)[i] = h;
    ((ushort4*)lo)[i] = l;
}

__global__ __launch_bounds__(256)
void cvt_bf16_kernel(const float* __restrict__ src, ushort* __restrict__ dst)
{
    const int i = blockIdx.x * 256 + threadIdx.x;
    float4 v = ((const float4*)src)[i];
    ushort4 h;
    h.x = f2bf(v.x); h.y = f2bf(v.y); h.z = f2bf(v.z); h.w = f2bf(v.w);
    ((ushort4*)dst)[i] = h;
}

// C[M,N] = A[M,K](bf16) * B[N,K]^T(bf16), fp32 accumulate.
// 128x128 block, 4 waves x (4x4 of 16x16x32 MFMA). Tiled LDS (see header).
// EPI: 0 = fp32 store, 1 = softplus(v + bias[col]) fp32, 2 = bf16 store.
template <int EPI>
__global__ __launch_bounds__(256)
void gemm_mfma(const ushort* __restrict__ A, const ushort* __restrict__ Bm,
               const float* __restrict__ bias, void* __restrict__ Cout,
               int N, int K)
{
    __shared__ ushort As[4096];   // 8 KB
    __shared__ ushort Bs[4096];   // 8 KB

    const int tid  = threadIdx.x;
    const int lane = tid & 63;
    const int wave = tid >> 6;
    const int wm   = (wave >> 1) * 64;
    const int wn   = (wave & 1) * 64;
    const int row0 = blockIdx.y * 128;
    const int col0 = blockIdx.x * 128;

    const int crow = tid >> 2;            // 0..63
    const int cq   = tid & 3;             // 16B chunk
    const ushort* Ag0 = A  + (size_t)(row0 + crow) * K + cq * 8;
    const ushort* Ag1 = A  + (size_t)(row0 + crow + 64) * K + cq * 8;
    const ushort* Bg0 = Bm + (size_t)(col0 + crow) * K + cq * 8;
    const ushort* Bg1 = Bm + (size_t)(col0 + crow + 64) * K + cq * 8;
    const int st0 = lds_addr(crow, cq);
    const int st1 = st0 + 2048;           // crow+64: (row>>4)+4 => +4*512

    // fragment read base: dense 1KB per (wave, tile): lane L -> +16B*L
    const int fra = ((wm >> 4) << 9) + ((lane >> 4) << 7) + ((lane & 15) << 3);
    const int frb = ((wn >> 4) << 9) + ((lane >> 4) << 7) + ((lane & 15) << 3);

    f32x4 acc[4][4];
#pragma unroll
    for (int mi = 0; mi < 4; ++mi)
#pragma unroll
        for (int ni = 0; ni < 4; ++ni)
            acc[mi][ni] = (f32x4){0.f, 0.f, 0.f, 0.f};

    uint4 ra0 = *(const uint4*)Ag0, ra1 = *(const uint4*)Ag1;
    uint4 rb0 = *(const uint4*)Bg0, rb1 = *(const uint4*)Bg1;

    for (int k0 = 0; k0 < K; k0 += 32) {
        __syncthreads();
        *(uint4*)(As + st0) = ra0;
        *(uint4*)(As + st1) = ra1;
        *(uint4*)(Bs + st0) = rb0;
        *(uint4*)(Bs + st1) = rb1;
        __syncthreads();
        if (k0 + 32 < K) {
            ra0 = *(const uint4*)(Ag0 + k0 + 32);
            ra1 = *(const uint4*)(Ag1 + k0 + 32);
            rb0 = *(const uint4*)(Bg0 + k0 + 32);
            rb1 = *(const uint4*)(Bg1 + k0 + 32);
        }
        bf16x8 af[4], bf[4];
#pragma unroll
        for (int mi = 0; mi < 4; ++mi)
            af[mi] = *(const bf16x8*)(As + fra + mi * 512);
#pragma unroll
        for (int ni = 0; ni < 4; ++ni)
            bf[ni] = *(const bf16x8*)(Bs + frb + ni * 512);
#pragma unroll
        for (int mi = 0; mi < 4; ++mi)
#pragma unroll
            for (int ni = 0; ni < 4; ++ni)
                acc[mi][ni] = __builtin_amdgcn_mfma_f32_16x16x32_bf16(
                    af[mi], bf[ni], acc[mi][ni], 0, 0, 0);
    }

#pragma unroll
    for (int mi = 0; mi < 4; ++mi) {
        const int rg = row0 + wm + mi * 16 + (lane >> 4) * 4;
#pragma unroll
        for (int ni = 0; ni < 4; ++ni) {
            const int cg = col0 + wn + ni * 16 + (lane & 15);
            f32x4 v = acc[mi][ni];
            if (EPI == 1) {
                const float bv = bias[cg];
#pragma unroll
                for (int r = 0; r < 4; ++r) v[r] = softplus_f(v[r] + bv);
            }
#pragma unroll
            for (int r = 0; r < 4; ++r) {
                if (EPI == 2)
                    ((ushort*)Cout)[(size_t)(rg + r) * N + cg] = f2bf(v[r]);
                else
                    ((float*)Cout)[(size_t)(rg + r) * N + cg] = v[r];
            }
        }
    }
}

// Split-K bc GEMM: part[ks] = xc[:, ks*256:(ks+1)*256] @ Wx^T slice.
// M=8192, N=32, K-slice=256. Grid (8, 64). Keeps hi/lo weight split
// (B/C feed the scan). Tiled conflict-free LDS.
__global__ __launch_bounds__(256)
void gemm_bc_mfma(const ushort* __restrict__ A, const ushort* __restrict__ Bh,
                  const ushort* __restrict__ Bl, float* __restrict__ part)
{
    __shared__ ushort As[4096];
    __shared__ ushort Bhs[1024];
    __shared__ ushort Bls[1024];

    const int tid  = threadIdx.x;
    const int lane = tid & 63;
    const int wave = tid >> 6;
    const int ks   = blockIdx.x;     // 0..7
    const int mb   = blockIdx.y;     // 0..63
    const int row0 = mb * 128;
    const int kb   = ks * 256;

    const int crow = tid >> 2;
    const int cq   = tid & 3;
    const ushort* Ag0 = A + (size_t)(row0 + crow) * 2048 + kb + cq * 8;
    const ushort* Ag1 = A + (size_t)(row0 + crow + 64) * 2048 + kb + cq * 8;
    const int st0 = lds_addr(crow, cq);
    const int st1 = st0 + 2048;

    const int t2   = tid & 127;
    const int brow = t2 >> 2;        // 0..31
    const int bq   = t2 & 3;
    const ushort* Bg = (tid < 128 ? Bh : Bl) + (size_t)brow * 2048 + kb + bq * 8;
    ushort* Bdst     = (tid < 128 ? Bhs : Bls) + lds_addr(brow, bq);

    const int wm  = wave * 32;
    const int fra = ((wm >> 4) << 9) + ((lane >> 4) << 7) + ((lane & 15) << 3);
    const int frb = ((lane >> 4) << 7) + ((lane & 15) << 3);

    f32x4 acc[2][2];
#pragma unroll
    for (int mi = 0; mi < 2; ++mi)
#pragma unroll
        for (int ni = 0; ni < 2; ++ni)
            acc[mi][ni] = (f32x4){0.f, 0.f, 0.f, 0.f};

    uint4 ra0 = *(const uint4*)Ag0, ra1 = *(const uint4*)Ag1;
    uint4 rb  = *(const uint4*)Bg;

    for (int kt = 0; kt < 8; ++kt) {
        __syncthreads();
        *(uint4*)(As + st0) = ra0;
        *(uint4*)(As + st1) = ra1;
        *(uint4*)Bdst = rb;
        __syncthreads();
        if (kt < 7) {
            ra0 = *(const uint4*)(Ag0 + (kt + 1) * 32);
            ra1 = *(const uint4*)(Ag1 + (kt + 1) * 32);
            rb  = *(const uint4*)(Bg + (kt + 1) * 32);
        }
        bf16x8 af[2], bhf[2], blf[2];
#pragma unroll
        for (int mi = 0; mi < 2; ++mi)
            af[mi] = *(const bf16x8*)(As + fra + mi * 512);
#pragma unroll
        for (int ni = 0; ni < 2; ++ni) {
            bhf[ni] = *(const bf16x8*)(Bhs + frb + ni * 512);
            blf[ni] = *(const bf16x8*)(Bls + frb + ni * 512);
        }
#pragma unroll
        for (int mi = 0; mi < 2; ++mi)
#pragma unroll
            for (int ni = 0; ni < 2; ++ni) {
                acc[mi][ni] = __builtin_amdgcn_mfma_f32_16x16x32_bf16(
                    af[mi], bhf[ni], acc[mi][ni], 0, 0, 0);
                acc[mi][ni] = __builtin_amdgcn_mfma_f32_16x16x32_bf16(
                    af[mi], blf[ni], acc[mi][ni], 0, 0, 0);
            }
    }

#pragma unroll
    for (int mi = 0; mi < 2; ++mi) {
        const int rg = row0 + wm + mi * 16 + (lane >> 4) * 4;
#pragma unroll
        for (int ni = 0; ni < 2; ++ni) {
            const int cg = ni * 16 + (lane & 15);
            f32x4 v = acc[mi][ni];
#pragma unroll
            for (int r = 0; r < 4; ++r)
                part[((size_t)ks * 8192 + rg + r) * 32 + cg] = v[r];
        }
    }
}

__global__ __launch_bounds__(256)
void bc_reduce_kernel(const float* __restrict__ part, float* __restrict__ bc)
{
    const int i = blockIdx.x * 256 + threadIdx.x;   // 262144
    float s = 0.f;
#pragma unroll
    for (int ks = 0; ks < 8; ++ks)
        s += part[(size_t)ks * 262144 + i];
    bc[i] = s;
}

// Depthwise causal conv1d (4 taps) + bias + silu; bf16 in, bf16 out.
__global__ __launch_bounds__(256)
void conv_silu_kernel(const ushort* __restrict__ xi, const float* __restrict__ cw,
                      const float* __restrict__ cb, ushort* __restrict__ xc)
{
    const int idx = blockIdx.x * 256 + threadIdx.x;
    const int e   = (idx & 511) << 2;
    const int row = idx >> 9;
    const int l   = row & 2047;

    const float4 w0 = *(const float4*)(cw + (size_t)(e + 0) * 4);
    const float4 w1 = *(const float4*)(cw + (size_t)(e + 1) * 4);
    const float4 w2 = *(const float4*)(cw + (size_t)(e + 2) * 4);
    const float4 w3 = *(const float4*)(cw + (size_t)(e + 3) * 4);

    float4 acc = *(const float4*)(cb + e);

#define CONV_TAP(K_, WSEL)                                                  \
    {                                                                       \
        ushort4 t = *(const ushort4*)(xi + (size_t)(row - (K_)) * 2048 + e);\
        acc.x = fmaf(bf2f(t.x), w0.WSEL, acc.x);                            \
        acc.y = fmaf(bf2f(t.y), w1.WSEL, acc.y);                            \
        acc.z = fmaf(bf2f(t.z), w2.WSEL, acc.z);                            \
        acc.w = fmaf(bf2f(t.w), w3.WSEL, acc.w);                            \
    }
    if (l >= 3) CONV_TAP(3, x)
    if (l >= 2) CONV_TAP(2, y)
    if (l >= 1) CONV_TAP(1, z)
    CONV_TAP(0, w)
#undef CONV_TAP

    ushort4 o;
    o.x = f2bf(silu_f(acc.x)); o.y = f2bf(silu_f(acc.y));
    o.z = f2bf(silu_f(acc.z)); o.w = f2bf(silu_f(acc.w));
    *(ushort4*)(xc + (size_t)row * 2048 + e) = o;
}

// ---- d-parallel chunked selective scan ----

// Pass 1: chunks 0..NCHK-2, h from 0, writes he + P = exp(A * sum dt).
__global__ __launch_bounds__(256)
void scan_part1(const ushort* __restrict__ xcb, const float* __restrict__ dbuf,
                const float* __restrict__ bcbuf, const float* __restrict__ A_log,
                float* __restrict__ sum_h, float* __restrict__ sum_p)
{
    const int c    = blockIdx.x >> 5;          // 0..14
    const int b    = (blockIdx.x >> 3) & 3;
    const int dblk = blockIdx.x & 7;
    const int d    = dblk * 256 + threadIdx.x;

    float Aval[16];
#pragma unroll
    for (int q = 0; q < 4; ++q) {
        float4 al = *(const float4*)(A_log + (size_t)d * 16 + q * 4);
        Aval[q*4+0] = -__expf(al.x); Aval[q*4+1] = -__expf(al.y);
        Aval[q*4+2] = -__expf(al.z); Aval[q*4+3] = -__expf(al.w);
    }

    const size_t row0 = (size_t)b * 2048 + (size_t)c * CLEN;
    const float*  dp  = dbuf + row0 * 2048 + d;
    const ushort* xp  = xcb  + row0 * 2048 + d;
    const float*  bcp = bcbuf + row0 * 32;

    float h[16];
#pragma unroll
    for (int s = 0; s < 16; ++s) h[s] = 0.f;
    float S = 0.f;

    float wdt[SW], wxv[SW];
#pragma unroll
    for (int j = 0; j < SW; ++j) {
        wdt[j] = dp[(size_t)j * 2048];
        wxv[j] = bf2f(xp[(size_t)j * 2048]);
    }
    float curB[16];
#pragma unroll
    for (int q = 0; q < 4; ++q)
        *(float4*)&curB[q*4] = *(const float4*)(bcp + q * 4);

    for (int l0 = 0; l0 < CLEN; l0 += SW) {
        float ndt[SW], nxv[SW];
        const bool more = (l0 + SW) < CLEN;
        if (more) {
#pragma unroll
            for (int j = 0; j < SW; ++j) {
                const size_t o = (size_t)(l0 + SW + j);
                ndt[j] = dp[o * 2048];
                nxv[j] = bf2f(xp[o * 2048]);
            }
        }
#pragma unroll
        for (int j = 0; j < SW; ++j) {
            const int l = l0 + j;
            float nB[16];
            if (l + 1 < CLEN) {
#pragma unroll
                for (int q = 0; q < 4; ++q)
                    *(float4*)&nB[q*4] = *(const float4*)(bcp + (size_t)(l+1) * 32 + q * 4);
            }
            const float dt = wdt[j];
            const float t  = dt * wxv[j];
            S += dt;
#pragma unroll
            for (int s = 0; s < 16; ++s)
                h[s] = __expf(dt * Aval[s]) * h[s] + curB[s] * t;
            if (l + 1 < CLEN) {
#pragma unroll
                for (int s = 0; s < 16; ++s) curB[s] = nB[s];
            }
        }
        if (more) {
#pragma unroll
            for (int j = 0; j < SW; ++j) { wdt[j] = ndt[j]; wxv[j] = nxv[j]; }
        }
    }

    float* sh = sum_h + ((((size_t)c * 4 + b) * 2048 + d) << 4);
    float* sp = sum_p + ((((size_t)c * 4 + b) * 2048 + d) << 4);
#pragma unroll
    for (int q = 0; q < 4; ++q) {
        *(float4*)(sh + q * 4) = make_float4(h[q*4], h[q*4+1], h[q*4+2], h[q*4+3]);
        *(float4*)(sp + q * 4) = make_float4(__expf(Aval[q*4] * S), __expf(Aval[q*4+1] * S),
                                             __expf(Aval[q*4+2] * S), __expf(Aval[q*4+3] * S));
    }
}

// Pass 2: all NCHK chunks; fold preceding summaries, scan, y bf16 out.
__global__ __launch_bounds__(256)
void scan_part2(const ushort* __restrict__ zbuf, const ushort* __restrict__ xcb,
                const float* __restrict__ dbuf, const float* __restrict__ bcbuf,
                const float* __restrict__ A_log, const float* __restrict__ Dp,
                const float* __restrict__ sum_h, const float* __restrict__ sum_p,
                ushort* __restrict__ ybuf)
{
    const int c    = blockIdx.x >> 5;          // 0..15
    const int b    = (blockIdx.x >> 3) & 3;
    const int dblk = blockIdx.x & 7;
    const int d    = dblk * 256 + threadIdx.x;

    float Aval[16];
#pragma unroll
    for (int q = 0; q < 4; ++q) {
        float4 al = *(const float4*)(A_log + (size_t)d * 16 + q * 4);
        Aval[q*4+0] = -__expf(al.x); Aval[q*4+1] = -__expf(al.y);
        Aval[q*4+2] = -__expf(al.z); Aval[q*4+3] = -__expf(al.w);
    }
    const float Dv = Dp[d];

    float h[16];
#pragma unroll
    for (int s = 0; s < 16; ++s) h[s] = 0.f;
    for (int j = 0; j < c; ++j) {              // fold chunk summaries
        const float* sh = sum_h + ((((size_t)j * 4 + b) * 2048 + d) << 4);
        const float* sp = sum_p + ((((size_t)j * 4 + b) * 2048 + d) << 4);
#pragma unroll
        for (int q = 0; q < 4; ++q) {
            float4 vh = *(const float4*)(sh + q * 4);
            float4 vp = *(const float4*)(sp + q * 4);
            h[q*4+0] = vh.x + vp.x * h[q*4+0];
            h[q*4+1] = vh.y + vp.y * h[q*4+1];
            h[q*4+2] = vh.z + vp.z * h[q*4+2];
            h[q*4+3] = vh.w + vp.w * h[q*4+3];
        }
    }

    const size_t row0 = (size_t)b * 2048 + (size_t)c * CLEN;
    const float*  dp  = dbuf + row0 * 2048 + d;
    const ushort* xp  = xcb  + row0 * 2048 + d;
    const ushort* zp  = zbuf + row0 * 2048 + d;
    const float*  bcp = bcbuf + row0 * 32;
    ushort*       yp  = ybuf + row0 * 2048 + d;

    float wdt[SW], wxv[SW], wzv[SW];
#pragma unroll
    for (int j = 0; j < SW; ++j) {
        wdt[j] = dp[(size_t)j * 2048];
        wxv[j] = bf2f(xp[(size_t)j * 2048]);
        wzv[j] = bf2f(zp[(size_t)j * 2048]);
    }
    float curB[16], curC[16];
#pragma unroll
    for (int q = 0; q < 4; ++q) {
        *(float4*)&curB[q*4] = *(const float4*)(bcp + q * 4);
        *(float4*)&curC[q*4] = *(const float4*)(bcp + 16 + q * 4);
    }

    for (int l0 = 0; l0 < CLEN; l0 += SW) {
        float ndt[SW], nxv[SW], nzv[SW];
        const bool more = (l0 + SW) < CLEN;
        if (more) {
#pragma unroll
            for (int j = 0; j < SW; ++j) {
                const size_t o = (size_t)(l0 + SW + j);
                ndt[j] = dp[o * 2048];
                nxv[j] = bf2f(xp[o * 2048]);
                nzv[j] = bf2f(zp[o * 2048]);
            }
        }
#pragma unroll
        for (int j = 0; j < SW; ++j) {
            const int l = l0 + j;
            float nB[16], nC[16];
            if (l + 1 < CLEN) {
#pragma unroll
                for (int q = 0; q < 4; ++q) {
                    *(float4*)&nB[q*4] = *(const float4*)(bcp + (size_t)(l+1) * 32 + q * 4);
                    *(float4*)&nC[q*4] = *(const float4*)(bcp + (size_t)(l+1) * 32 + 16 + q * 4);
                }
            }
            const float dt = wdt[j];
            const float t  = dt * wxv[j];
#pragma unroll
            for (int s = 0; s < 16; ++s)
                h[s] = __expf(dt * Aval[s]) * h[s] + curB[s] * t;
            float y0 = 0.f, y1 = 0.f, y2 = 0.f, y3 = 0.f;
#pragma unroll
            for (int s = 0; s < 16; s += 4) {
                y0 = fmaf(h[s+0], curC[s+0], y0);
                y1 = fmaf(h[s+1], curC[s+1], y1);
                y2 = fmaf(h[s+2], curC[s+2], y2);
                y3 = fmaf(h[s+3], curC[s+3], y3);
            }
            float y = (y0 + y1) + (y2 + y3) + Dv * wxv[j];
            yp[(size_t)l * 2048] = f2bf(y * silu_f(wzv[j]));
            if (l + 1 < CLEN) {
#pragma unroll
                for (int s = 0; s < 16; ++s) { curB[s] = nB[s]; curC[s] = nC[s]; }
            }
        }
        if (more) {
#pragma unroll
            for (int j = 0; j < SW; ++j) {
                wdt[j] = ndt[j]; wxv[j] = nxv[j]; wzv[j] = nzv[j];
            }
        }
    }
}

extern "C" void kernel_launch(void* const* d_in, const int* in_sizes, int n_in,
                              void* d_out, int out_size, void* d_ws, size_t ws_size,
                              hipStream_t stream)
{
    const float* x          = (const float*)d_in[0];
    const float* in_proj_w  = (const float*)d_in[1];
    const float* conv_w     = (const float*)d_in[2];
    const float* conv_b     = (const float*)d_in[3];
    const float* x_proj_w   = (const float*)d_in[4];
    const float* dt_proj_w  = (const float*)d_in[5];
    const float* dt_proj_b  = (const float*)d_in[6];
    const float* A_log      = (const float*)d_in[7];
    const float* Dp         = (const float*)d_in[8];
    const float* out_proj_w = (const float*)d_in[9];
    float* out = (float*)d_out;

    ushort* XI    = (ushort*)d_ws;                    // 32 MB; later Y'
    ushort* Z     = XI + 16777216;                    // 32 MB
    ushort* XC2   = Z + 16777216;                     // 32 MB
    float*  DELTA = (float*)(XC2 + 16777216);         // 64 MB
    ushort* XP    = (ushort*)DELTA;                   // x' bf16 (pre-DELTA)
    ushort* WINH  = (ushort*)(DELTA + 16777216);      // 8 MB [4096,1024] bf16
    ushort* WINL  = WINH + 4194304;                   // 8 MB (unused now)
    ushort* WDTH  = WINL + 4194304;                   // 8 MB [2048,2048] bf16
    ushort* WDTL  = WDTH + 4194304;                   // 8 MB (unused now)
    ushort* WOUTH = WDTL + 4194304;                   // 4 MB [1024,2048] bf16
    ushort* WOUTL = WOUTH + 2097152;                  // 4 MB (unused now)
    float*  BC    = (float*)(WOUTL + 2097152);        // 1 MB
    float*  SUMH  = BC + 262144;                      // 8 MB
    float*  SUMP  = SUMH + 2097152;                   // 8 MB
    ushort* XPH   = (ushort*)(SUMP + 2097152);        // 128 KB (x_proj hi)
    ushort* XPL   = XPH + 65536;                      // 128 KB
    float*  PART  = (float*)(XPL + 65536);            // 8 MB split-K partials
    ushort* Yp    = XI;

    const dim3 blk(256);

    // 0) conversions (weights plain bf16 except x_proj hi/lo)
    cvt_bf16_kernel<<<dim3(8192), blk, 0, stream>>>(x, XP);
    cvt_bf16_kernel<<<dim3(4096), blk, 0, stream>>>(in_proj_w, WINH);
    cvt_bf16_kernel<<<dim3(4096), blk, 0, stream>>>(dt_proj_w, WDTH);
    cvt_bf16_kernel<<<dim3(2048), blk, 0, stream>>>(out_proj_w, WOUTH);
    split_w_kernel<<<dim3(64),    blk, 0, stream>>>(x_proj_w, XPH, XPL);

    // 1) xi, z
    gemm_mfma<2><<<dim3(16, 64), blk, 0, stream>>>(XP, WINH, nullptr, XI, 2048, 1024);
    gemm_mfma<2><<<dim3(16, 64), blk, 0, stream>>>(XP, WINH + 2097152, nullptr, Z, 2048, 1024);

    // 2) xc = silu(conv(xi) + b)
    conv_silu_kernel<<<dim3(16384), blk, 0, stream>>>(XI, conv_w, conv_b, XC2);

    // 3) delta = softplus(xc @ Wdt^T + b)
    gemm_mfma<1><<<dim3(16, 64), blk, 0, stream>>>(XC2, WDTH, dt_proj_b, DELTA, 2048, 2048);

    // 4) bc = xc @ x_proj_w^T  (split-K MFMA + reduce)
    gemm_bc_mfma<<<dim3(8, 64), blk, 0, stream>>>(XC2, XPH, XPL, PART);
    bc_reduce_kernel<<<dim3(1024), blk, 0, stream>>>(PART, BC);

    // 5) chunked scan: pass1 (chunks 0..14) then pass2 (all 16)
    scan_part1<<<dim3((NCHK - 1) * 32), blk, 0, stream>>>(XC2, DELTA, BC, A_log, SUMH, SUMP);
    scan_part2<<<dim3(NCHK * 32), blk, 0, stream>>>(Z, XC2, DELTA, BC, A_log, Dp,
                                                    SUMH, SUMP, Yp);

    // 6) out = y @ Wout^T
    gemm_mfma<0><<<dim3(8, 64), blk, 0, stream>>>(Yp, WOUTH, nullptr, out, 1024, 2048);
}

// Round 10
// 626.309 us; speedup vs baseline: 1.1819x; 1.0280x over previous
//
#include <hip/hip_runtime.h>
#include <hip/hip_bf16.h>

// MambaMinimalBlock: B=4, L=2048, D_MODEL=1024, D_STATE=16, D_CONV=4,
// D_INNER=2048, BL=8192. fp32 in/out.
//
// R10: XOR-swizzled LDS layout. 16B chunk (row,q) stored at byte
//   row*64 + ((q + (row>>1)) & 3) * 16.
// Under 8-lane phase processing both staging writes (crow=tid>>2,cq=tid&3)
// and MFMA fragment reads (r=lane&15,q=lane>>4) cover all 8 bank-quads
// exactly once per phase => zero conflicts, 16B-aligned b128 kept.
// (R9 "tiled" layout measured 2.52e7 SQ_LDS_BANK_CONFLICT — 4-way write
// conflicts; LDS traffic is the binding pipe: 48KB/block/K-tile vs ~78cyc
// MFMA. R7 linear: 1.26e7 read conflicts. Swizzle fixes both sides.)
//
// GEMMs: plain bf16 (weights+activations, fp32 acc) — absmax 1.95e-3 vs
// 5.59e-3 threshold. bc keeps hi/lo weight split. Scan: d-parallel chunked.

typedef float  f32x4  __attribute__((ext_vector_type(4)));
typedef short  bf16x8 __attribute__((ext_vector_type(8)));

#define NCHK 16
#define CLEN 128
#define SW   8      // scan window (double-buffered)

__device__ __forceinline__ ushort f2bf(float f) {
    uint u = __float_as_uint(f);
    u += 0x7FFF + ((u >> 16) & 1);          // RNE
    return (ushort)(u >> 16);
}
__device__ __forceinline__ float bf2f(ushort h) {
    return __uint_as_float((uint)h << 16);
}
__device__ __forceinline__ float softplus_f(float x) {
    return fmaxf(x, 0.f) + __logf(1.f + __expf(-fabsf(x)));
}
__device__ __forceinline__ float silu_f(float x) {
    return x / (1.f + __expf(-x));
}

// swizzled LDS chunk address (ushort units): row stride 32, chunk q
// permuted by row: c = (q + (row>>1)) & 3.
__device__ __forceinline__ int lds_addr(int row, int q) {
    return (row << 5) + ((((q + (row >> 1)) & 3)) << 3);
}
// fragment-read lane offset within a 16-row tile (tile base ≡ 0 mod 16 rows
// => swizzle term reduces to (q + (r>>1)) & 3, tile-independent).
__device__ __forceinline__ int lds_frag_off(int lane) {
    const int r = lane & 15, q = lane >> 4;
    return (r << 5) + ((((q + (r >> 1)) & 3)) << 3);
}

__global__ __launch_bounds__(256)
void split_w_kernel(const float* __restrict__ src, ushort* __restrict__ hi,
                    ushort* __restrict__ lo)
{
    const int i = blockIdx.x * 256 + threadIdx.x;
    float4 v = ((const float4*)src)[i];
    ushort4 h, l;
    h.x = f2bf(v.x); l.x = f2bf(v.x - bf2f(h.x));
    h.y = f2bf(v.y); l.y = f2bf(v.y - bf2f(h.y));
    h.z = f2bf(v.z); l.z = f2bf(v.z - bf2f(h.z));
    h.w = f2bf(v.w); l.w = f2bf(v.w - bf2f(h.w));
    ((ushort4*)hi)[i] = h;
    ((ushort4*)lo)[i] = l;
}

__global__ __launch_bounds__(256)
void cvt_bf16_kernel(const float* __restrict__ src, ushort* __restrict__ dst)
{
    const int i = blockIdx.x * 256 + threadIdx.x;
    float4 v = ((const float4*)src)[i];
    ushort4 h;
    h.x = f2bf(v.x); h.y = f2bf(v.y); h.z = f2bf(v.z); h.w = f2bf(v.w);
    ((ushort4*)dst)[i] = h;
}

// C[M,N] = A[M,K](bf16) * B[N,K]^T(bf16), fp32 accumulate.
// 128x128 block, 4 waves x (4x4 of 16x16x32 MFMA). Swizzled LDS.
// EPI: 0 = fp32 store, 1 = softplus(v + bias[col]) fp32, 2 = bf16 store.
template <int EPI>
__global__ __launch_bounds__(256)
void gemm_mfma(const ushort* __restrict__ A, const ushort* __restrict__ Bm,
               const float* __restrict__ bias, void* __restrict__ Cout,
               int N, int K)
{
    __shared__ ushort As[4096];   // 8 KB
    __shared__ ushort Bs[4096];   // 8 KB

    const int tid  = threadIdx.x;
    const int lane = tid & 63;
    const int wave = tid >> 6;
    const int wm   = (wave >> 1) * 64;
    const int wn   = (wave & 1) * 64;
    const int row0 = blockIdx.y * 128;
    const int col0 = blockIdx.x * 128;

    const int crow = tid >> 2;            // 0..63
    const int cq   = tid & 3;             // 16B chunk
    const ushort* Ag0 = A  + (size_t)(row0 + crow) * K + cq * 8;
    const ushort* Ag1 = A  + (size_t)(row0 + crow + 64) * K + cq * 8;
    const ushort* Bg0 = Bm + (size_t)(col0 + crow) * K + cq * 8;
    const ushort* Bg1 = Bm + (size_t)(col0 + crow + 64) * K + cq * 8;
    const int st0 = lds_addr(crow, cq);
    const int st1 = st0 + 2048;           // row+64: same swizzle, +64*32

    const int flo = lds_frag_off(lane);
    const int fra = (wm << 5) + flo;
    const int frb = (wn << 5) + flo;

    f32x4 acc[4][4];
#pragma unroll
    for (int mi = 0; mi < 4; ++mi)
#pragma unroll
        for (int ni = 0; ni < 4; ++ni)
            acc[mi][ni] = (f32x4){0.f, 0.f, 0.f, 0.f};

    uint4 ra0 = *(const uint4*)Ag0, ra1 = *(const uint4*)Ag1;
    uint4 rb0 = *(const uint4*)Bg0, rb1 = *(const uint4*)Bg1;

    for (int k0 = 0; k0 < K; k0 += 32) {
        __syncthreads();
        *(uint4*)(As + st0) = ra0;
        *(uint4*)(As + st1) = ra1;
        *(uint4*)(Bs + st0) = rb0;
        *(uint4*)(Bs + st1) = rb1;
        __syncthreads();
        if (k0 + 32 < K) {
            ra0 = *(const uint4*)(Ag0 + k0 + 32);
            ra1 = *(const uint4*)(Ag1 + k0 + 32);
            rb0 = *(const uint4*)(Bg0 + k0 + 32);
            rb1 = *(const uint4*)(Bg1 + k0 + 32);
        }
        bf16x8 af[4], bf[4];
#pragma unroll
        for (int mi = 0; mi < 4; ++mi)
            af[mi] = *(const bf16x8*)(As + fra + mi * 512);
#pragma unroll
        for (int ni = 0; ni < 4; ++ni)
            bf[ni] = *(const bf16x8*)(Bs + frb + ni * 512);
#pragma unroll
        for (int mi = 0; mi < 4; ++mi)
#pragma unroll
            for (int ni = 0; ni < 4; ++ni)
                acc[mi][ni] = __builtin_amdgcn_mfma_f32_16x16x32_bf16(
                    af[mi], bf[ni], acc[mi][ni], 0, 0, 0);
    }

#pragma unroll
    for (int mi = 0; mi < 4; ++mi) {
        const int rg = row0 + wm + mi * 16 + (lane >> 4) * 4;
#pragma unroll
        for (int ni = 0; ni < 4; ++ni) {
            const int cg = col0 + wn + ni * 16 + (lane & 15);
            f32x4 v = acc[mi][ni];
            if (EPI == 1) {
                const float bv = bias[cg];
#pragma unroll
                for (int r = 0; r < 4; ++r) v[r] = softplus_f(v[r] + bv);
            }
#pragma unroll
            for (int r = 0; r < 4; ++r) {
                if (EPI == 2)
                    ((ushort*)Cout)[(size_t)(rg + r) * N + cg] = f2bf(v[r]);
                else
                    ((float*)Cout)[(size_t)(rg + r) * N + cg] = v[r];
            }
        }
    }
}

// Split-K bc GEMM: part[ks] = xc[:, ks*256:(ks+1)*256] @ Wx^T slice.
// M=8192, N=32, K-slice=256. Grid (8, 64). hi/lo weight split. Swizzled LDS.
__global__ __launch_bounds__(256)
void gemm_bc_mfma(const ushort* __restrict__ A, const ushort* __restrict__ Bh,
                  const ushort* __restrict__ Bl, float* __restrict__ part)
{
    __shared__ ushort As[4096];
    __shared__ ushort Bhs[1024];
    __shared__ ushort Bls[1024];

    const int tid  = threadIdx.x;
    const int lane = tid & 63;
    const int wave = tid >> 6;
    const int ks   = blockIdx.x;     // 0..7
    const int mb   = blockIdx.y;     // 0..63
    const int row0 = mb * 128;
    const int kb   = ks * 256;

    const int crow = tid >> 2;
    const int cq   = tid & 3;
    const ushort* Ag0 = A + (size_t)(row0 + crow) * 2048 + kb + cq * 8;
    const ushort* Ag1 = A + (size_t)(row0 + crow + 64) * 2048 + kb + cq * 8;
    const int st0 = lds_addr(crow, cq);
    const int st1 = st0 + 2048;

    const int t2   = tid & 127;
    const int brow = t2 >> 2;        // 0..31
    const int bq   = t2 & 3;
    const ushort* Bg = (tid < 128 ? Bh : Bl) + (size_t)brow * 2048 + kb + bq * 8;
    ushort* Bdst     = (tid < 128 ? Bhs : Bls) + lds_addr(brow, bq);

    const int wm  = wave * 32;
    const int flo = lds_frag_off(lane);
    const int fra = (wm << 5) + flo;
    const int frb = flo;

    f32x4 acc[2][2];
#pragma unroll
    for (int mi = 0; mi < 2; ++mi)
#pragma unroll
        for (int ni = 0; ni < 2; ++ni)
            acc[mi][ni] = (f32x4){0.f, 0.f, 0.f, 0.f};

    uint4 ra0 = *(const uint4*)Ag0, ra1 = *(const uint4*)Ag1;
    uint4 rb  = *(const uint4*)Bg;

    for (int kt = 0; kt < 8; ++kt) {
        __syncthreads();
        *(uint4*)(As + st0) = ra0;
        *(uint4*)(As + st1) = ra1;
        *(uint4*)Bdst = rb;
        __syncthreads();
        if (kt < 7) {
            ra0 = *(const uint4*)(Ag0 + (kt + 1) * 32);
            ra1 = *(const uint4*)(Ag1 + (kt + 1) * 32);
            rb  = *(const uint4*)(Bg + (kt + 1) * 32);
        }
        bf16x8 af[2], bhf[2], blf[2];
#pragma unroll
        for (int mi = 0; mi < 2; ++mi)
            af[mi] = *(const bf16x8*)(As + fra + mi * 512);
#pragma unroll
        for (int ni = 0; ni < 2; ++ni) {
            bhf[ni] = *(const bf16x8*)(Bhs + frb + ni * 512);
            blf[ni] = *(const bf16x8*)(Bls + frb + ni * 512);
        }
#pragma unroll
        for (int mi = 0; mi < 2; ++mi)
#pragma unroll
            for (int ni = 0; ni < 2; ++ni) {
                acc[mi][ni] = __builtin_amdgcn_mfma_f32_16x16x32_bf16(
                    af[mi], bhf[ni], acc[mi][ni], 0, 0, 0);
                acc[mi][ni] = __builtin_amdgcn_mfma_f32_16x16x32_bf16(
                    af[mi], blf[ni], acc[mi][ni], 0, 0, 0);
            }
    }

#pragma unroll
    for (int mi = 0; mi < 2; ++mi) {
        const int rg = row0 + wm + mi * 16 + (lane >> 4) * 4;
#pragma unroll
        for (int ni = 0; ni < 2; ++ni) {
            const int cg = ni * 16 + (lane & 15);
            f32x4 v = acc[mi][ni];
#pragma unroll
            for (int r = 0; r < 4; ++r)
                part[((size_t)ks * 8192 + rg + r) * 32 + cg] = v[r];
        }
    }
}

__global__ __launch_bounds__(256)
void bc_reduce_kernel(const float* __restrict__ part, float* __restrict__ bc)
{
    const int i = blockIdx.x * 256 + threadIdx.x;   // 262144
    float s = 0.f;
#pragma unroll
    for (int ks = 0; ks < 8; ++ks)
        s += part[(size_t)ks * 262144 + i];
    bc[i] = s;
}

// Depthwise causal conv1d (4 taps) + bias + silu; bf16 in, bf16 out.
__global__ __launch_bounds__(256)
void conv_silu_kernel(const ushort* __restrict__ xi, const float* __restrict__ cw,
                      const float* __restrict__ cb, ushort* __restrict__ xc)
{
    const int idx = blockIdx.x * 256 + threadIdx.x;
    const int e   = (idx & 511) << 2;
    const int row = idx >> 9;
    const int l   = row & 2047;

    const float4 w0 = *(const float4*)(cw + (size_t)(e + 0) * 4);
    const float4 w1 = *(const float4*)(cw + (size_t)(e + 1) * 4);
    const float4 w2 = *(const float4*)(cw + (size_t)(e + 2) * 4);
    const float4 w3 = *(const float4*)(cw + (size_t)(e + 3) * 4);

    float4 acc = *(const float4*)(cb + e);

#define CONV_TAP(K_, WSEL)                                                  \
    {                                                                       \
        ushort4 t = *(const ushort4*)(xi + (size_t)(row - (K_)) * 2048 + e);\
        acc.x = fmaf(bf2f(t.x), w0.WSEL, acc.x);                            \
        acc.y = fmaf(bf2f(t.y), w1.WSEL, acc.y);                            \
        acc.z = fmaf(bf2f(t.z), w2.WSEL, acc.z);                            \
        acc.w = fmaf(bf2f(t.w), w3.WSEL, acc.w);                            \
    }
    if (l >= 3) CONV_TAP(3, x)
    if (l >= 2) CONV_TAP(2, y)
    if (l >= 1) CONV_TAP(1, z)
    CONV_TAP(0, w)
#undef CONV_TAP

    ushort4 o;
    o.x = f2bf(silu_f(acc.x)); o.y = f2bf(silu_f(acc.y));
    o.z = f2bf(silu_f(acc.z)); o.w = f2bf(silu_f(acc.w));
    *(ushort4*)(xc + (size_t)row * 2048 + e) = o;
}

// ---- d-parallel chunked selective scan ----

// Pass 1: chunks 0..NCHK-2, h from 0, writes he + P = exp(A * sum dt).
__global__ __launch_bounds__(256)
void scan_part1(const ushort* __restrict__ xcb, const float* __restrict__ dbuf,
                const float* __restrict__ bcbuf, const float* __restrict__ A_log,
                float* __restrict__ sum_h, float* __restrict__ sum_p)
{
    const int c    = blockIdx.x >> 5;          // 0..14
    const int b    = (blockIdx.x >> 3) & 3;
    const int dblk = blockIdx.x & 7;
    const int d    = dblk * 256 + threadIdx.x;

    float Aval[16];
#pragma unroll
    for (int q = 0; q < 4; ++q) {
        float4 al = *(const float4*)(A_log + (size_t)d * 16 + q * 4);
        Aval[q*4+0] = -__expf(al.x); Aval[q*4+1] = -__expf(al.y);
        Aval[q*4+2] = -__expf(al.z); Aval[q*4+3] = -__expf(al.w);
    }

    const size_t row0 = (size_t)b * 2048 + (size_t)c * CLEN;
    const float*  dp  = dbuf + row0 * 2048 + d;
    const ushort* xp  = xcb  + row0 * 2048 + d;
    const float*  bcp = bcbuf + row0 * 32;

    float h[16];
#pragma unroll
    for (int s = 0; s < 16; ++s) h[s] = 0.f;
    float S = 0.f;

    float wdt[SW], wxv[SW];
#pragma unroll
    for (int j = 0; j < SW; ++j) {
        wdt[j] = dp[(size_t)j * 2048];
        wxv[j] = bf2f(xp[(size_t)j * 2048]);
    }
    float curB[16];
#pragma unroll
    for (int q = 0; q < 4; ++q)
        *(float4*)&curB[q*4] = *(const float4*)(bcp + q * 4);

    for (int l0 = 0; l0 < CLEN; l0 += SW) {
        float ndt[SW], nxv[SW];
        const bool more = (l0 + SW) < CLEN;
        if (more) {
#pragma unroll
            for (int j = 0; j < SW; ++j) {
                const size_t o = (size_t)(l0 + SW + j);
                ndt[j] = dp[o * 2048];
                nxv[j] = bf2f(xp[o * 2048]);
            }
        }
#pragma unroll
        for (int j = 0; j < SW; ++j) {
            const int l = l0 + j;
            float nB[16];
            if (l + 1 < CLEN) {
#pragma unroll
                for (int q = 0; q < 4; ++q)
                    *(float4*)&nB[q*4] = *(const float4*)(bcp + (size_t)(l+1) * 32 + q * 4);
            }
            const float dt = wdt[j];
            const float t  = dt * wxv[j];
            S += dt;
#pragma unroll
            for (int s = 0; s < 16; ++s)
                h[s] = __expf(dt * Aval[s]) * h[s] + curB[s] * t;
            if (l + 1 < CLEN) {
#pragma unroll
                for (int s = 0; s < 16; ++s) curB[s] = nB[s];
            }
        }
        if (more) {
#pragma unroll
            for (int j = 0; j < SW; ++j) { wdt[j] = ndt[j]; wxv[j] = nxv[j]; }
        }
    }

    float* sh = sum_h + ((((size_t)c * 4 + b) * 2048 + d) << 4);
    float* sp = sum_p + ((((size_t)c * 4 + b) * 2048 + d) << 4);
#pragma unroll
    for (int q = 0; q < 4; ++q) {
        *(float4*)(sh + q * 4) = make_float4(h[q*4], h[q*4+1], h[q*4+2], h[q*4+3]);
        *(float4*)(sp + q * 4) = make_float4(__expf(Aval[q*4] * S), __expf(Aval[q*4+1] * S),
                                             __expf(Aval[q*4+2] * S), __expf(Aval[q*4+3] * S));
    }
}

// Pass 2: all NCHK chunks; fold preceding summaries, scan, y bf16 out.
__global__ __launch_bounds__(256)
void scan_part2(const ushort* __restrict__ zbuf, const ushort* __restrict__ xcb,
                const float* __restrict__ dbuf, const float* __restrict__ bcbuf,
                const float* __restrict__ A_log, const float* __restrict__ Dp,
                const float* __restrict__ sum_h, const float* __restrict__ sum_p,
                ushort* __restrict__ ybuf)
{
    const int c    = blockIdx.x >> 5;          // 0..15
    const int b    = (blockIdx.x >> 3) & 3;
    const int dblk = blockIdx.x & 7;
    const int d    = dblk * 256 + threadIdx.x;

    float Aval[16];
#pragma unroll
    for (int q = 0; q < 4; ++q) {
        float4 al = *(const float4*)(A_log + (size_t)d * 16 + q * 4);
        Aval[q*4+0] = -__expf(al.x); Aval[q*4+1] = -__expf(al.y);
        Aval[q*4+2] = -__expf(al.z); Aval[q*4+3] = -__expf(al.w);
    }
    const float Dv = Dp[d];

    float h[16];
#pragma unroll
    for (int s = 0; s < 16; ++s) h[s] = 0.f;
    for (int j = 0; j < c; ++j) {              // fold chunk summaries
        const float* sh = sum_h + ((((size_t)j * 4 + b) * 2048 + d) << 4);
        const float* sp = sum_p + ((((size_t)j * 4 + b) * 2048 + d) << 4);
#pragma unroll
        for (int q = 0; q < 4; ++q) {
            float4 vh = *(const float4*)(sh + q * 4);
            float4 vp = *(const float4*)(sp + q * 4);
            h[q*4+0] = vh.x + vp.x * h[q*4+0];
            h[q*4+1] = vh.y + vp.y * h[q*4+1];
            h[q*4+2] = vh.z + vp.z * h[q*4+2];
            h[q*4+3] = vh.w + vp.w * h[q*4+3];
        }
    }

    const size_t row0 = (size_t)b * 2048 + (size_t)c * CLEN;
    const float*  dp  = dbuf + row0 * 2048 + d;
    const ushort* xp  = xcb  + row0 * 2048 + d;
    const ushort* zp  = zbuf + row0 * 2048 + d;
    const float*  bcp = bcbuf + row0 * 32;
    ushort*       yp  = ybuf + row0 * 2048 + d;

    float wdt[SW], wxv[SW], wzv[SW];
#pragma unroll
    for (int j = 0; j < SW; ++j) {
        wdt[j] = dp[(size_t)j * 2048];
        wxv[j] = bf2f(xp[(size_t)j * 2048]);
        wzv[j] = bf2f(zp[(size_t)j * 2048]);
    }
    float curB[16], curC[16];
#pragma unroll
    for (int q = 0; q < 4; ++q) {
        *(float4*)&curB[q*4] = *(const float4*)(bcp + q * 4);
        *(float4*)&curC[q*4] = *(const float4*)(bcp + 16 + q * 4);
    }

    for (int l0 = 0; l0 < CLEN; l0 += SW) {
        float ndt[SW], nxv[SW], nzv[SW];
        const bool more = (l0 + SW) < CLEN;
        if (more) {
#pragma unroll
            for (int j = 0; j < SW; ++j) {
                const size_t o = (size_t)(l0 + SW + j);
                ndt[j] = dp[o * 2048];
                nxv[j] = bf2f(xp[o * 2048]);
                nzv[j] = bf2f(zp[o * 2048]);
            }
        }
#pragma unroll
        for (int j = 0; j < SW; ++j) {
            const int l = l0 + j;
            float nB[16], nC[16];
            if (l + 1 < CLEN) {
#pragma unroll
                for (int q = 0; q < 4; ++q) {
                    *(float4*)&nB[q*4] = *(const float4*)(bcp + (size_t)(l+1) * 32 + q * 4);
                    *(float4*)&nC[q*4] = *(const float4*)(bcp + (size_t)(l+1) * 32 + 16 + q * 4);
                }
            }
            const float dt = wdt[j];
            const float t  = dt * wxv[j];
#pragma unroll
            for (int s = 0; s < 16; ++s)
                h[s] = __expf(dt * Aval[s]) * h[s] + curB[s] * t;
            float y0 = 0.f, y1 = 0.f, y2 = 0.f, y3 = 0.f;
#pragma unroll
            for (int s = 0; s < 16; s += 4) {
                y0 = fmaf(h[s+0], curC[s+0], y0);
                y1 = fmaf(h[s+1], curC[s+1], y1);
                y2 = fmaf(h[s+2], curC[s+2], y2);
                y3 = fmaf(h[s+3], curC[s+3], y3);
            }
            float y = (y0 + y1) + (y2 + y3) + Dv * wxv[j];
            yp[(size_t)l * 2048] = f2bf(y * silu_f(wzv[j]));
            if (l + 1 < CLEN) {
#pragma unroll
                for (int s = 0; s < 16; ++s) { curB[s] = nB[s]; curC[s] = nC[s]; }
            }
        }
        if (more) {
#pragma unroll
            for (int j = 0; j < SW; ++j) {
                wdt[j] = ndt[j]; wxv[j] = nxv[j]; wzv[j] = nzv[j];
            }
        }
    }
}

extern "C" void kernel_launch(void* const* d_in, const int* in_sizes, int n_in,
                              void* d_out, int out_size, void* d_ws, size_t ws_size,
                              hipStream_t stream)
{
    const float* x          = (const float*)d_in[0];
    const float* in_proj_w  = (const float*)d_in[1];
    const float* conv_w     = (const float*)d_in[2];
    const float* conv_b     = (const float*)d_in[3];
    const float* x_proj_w   = (const float*)d_in[4];
    const float* dt_proj_w  = (const float*)d_in[5];
    const float* dt_proj_b  = (const float*)d_in[6];
    const float* A_log      = (const float*)d_in[7];
    const float* Dp         = (const float*)d_in[8];
    const float* out_proj_w = (const float*)d_in[9];
    float* out = (float*)d_out;

    ushort* XI    = (ushort*)d_ws;                    // 32 MB; later Y'
    ushort* Z     = XI + 16777216;                    // 32 MB
    ushort* XC2   = Z + 16777216;                     // 32 MB
    float*  DELTA = (float*)(XC2 + 16777216);         // 64 MB
    ushort* XP    = (ushort*)DELTA;                   // x' bf16 (pre-DELTA)
    ushort* WINH  = (ushort*)(DELTA + 16777216);      // 8 MB [4096,1024] bf16
    ushort* WINL  = WINH + 4194304;                   // 8 MB (unused)
    ushort* WDTH  = WINL + 4194304;                   // 8 MB [2048,2048] bf16
    ushort* WDTL  = WDTH + 4194304;                   // 8 MB (unused)
    ushort* WOUTH = WDTL + 4194304;                   // 4 MB [1024,2048] bf16
    ushort* WOUTL = WOUTH + 2097152;                  // 4 MB (unused)
    float*  BC    = (float*)(WOUTL + 2097152);        // 1 MB
    float*  SUMH  = BC + 262144;                      // 8 MB
    float*  SUMP  = SUMH + 2097152;                   // 8 MB
    ushort* XPH   = (ushort*)(SUMP + 2097152);        // 128 KB (x_proj hi)
    ushort* XPL   = XPH + 65536;                      // 128 KB
    float*  PART  = (float*)(XPL + 65536);            // 8 MB split-K partials
    ushort* Yp    = XI;

    const dim3 blk(256);

    // 0) conversions (weights plain bf16 except x_proj hi/lo)
    cvt_bf16_kernel<<<dim3(8192), blk, 0, stream>>>(x, XP);
    cvt_bf16_kernel<<<dim3(4096), blk, 0, stream>>>(in_proj_w, WINH);
    cvt_bf16_kernel<<<dim3(4096), blk, 0, stream>>>(dt_proj_w, WDTH);
    cvt_bf16_kernel<<<dim3(2048), blk, 0, stream>>>(out_proj_w, WOUTH);
    split_w_kernel<<<dim3(64),    blk, 0, stream>>>(x_proj_w, XPH, XPL);

    // 1) xi, z
    gemm_mfma<2><<<dim3(16, 64), blk, 0, stream>>>(XP, WINH, nullptr, XI, 2048, 1024);
    gemm_mfma<2><<<dim3(16, 64), blk, 0, stream>>>(XP, WINH + 2097152, nullptr, Z, 2048, 1024);

    // 2) xc = silu(conv(xi) + b)
    conv_silu_kernel<<<dim3(16384), blk, 0, stream>>>(XI, conv_w, conv_b, XC2);

    // 3) delta = softplus(xc @ Wdt^T + b)
    gemm_mfma<1><<<dim3(16, 64), blk, 0, stream>>>(XC2, WDTH, dt_proj_b, DELTA, 2048, 2048);

    // 4) bc = xc @ x_proj_w^T  (split-K MFMA + reduce)
    gemm_bc_mfma<<<dim3(8, 64), blk, 0, stream>>>(XC2, XPH, XPL, PART);
    bc_reduce_kernel<<<dim3(1024), blk, 0, stream>>>(PART, BC);

    // 5) chunked scan: pass1 (chunks 0..14) then pass2 (all 16)
    scan_part1<<<dim3((NCHK - 1) * 32), blk, 0, stream>>>(XC2, DELTA, BC, A_log, SUMH, SUMP);
    scan_part2<<<dim3(NCHK * 32), blk, 0, stream>>>(Z, XC2, DELTA, BC, A_log, Dp,
                                                    SUMH, SUMP, Yp);

    // 6) out = y @ Wout^T
    gemm_mfma<0><<<dim3(8, 64), blk, 0, stream>>>(Yp, WOUTH, nullptr, out, 1024, 2048);
}

// Round 11
// 613.849 us; speedup vs baseline: 1.2059x; 1.0203x over previous
//
#include <hip/hip_runtime.h>
#include <hip/hip_bf16.h>

// MambaMinimalBlock: B=4, L=2048, D_MODEL=1024, D_STATE=16, D_CONV=4,
// D_INNER=2048, BL=8192. fp32 in/out.
//
// R11: scan chunk count NCHK 16->32 (CLEN 64). Chunked-scan total work is
// NCHK-invariant; pass2 grid goes 2048->4096 waves (2->4 waves/SIMD).
// R10 counters: scan_part2 110us, VALUBusy 49%, occupancy 19% — grid-
// limited latency hiding, per-step depth-1 B/C L2 loads (~200cyc) vs
// ~210cyc compute with only 2 waves to interleave.
//
// GEMMs: plain bf16 MFMA (fp32 acc), XOR-swizzled LDS (R10: zero
// conflicts). bc: split-K MFMA with hi/lo weight split. absmax 1.95e-3
// vs 5.59e-3 threshold.

typedef float  f32x4  __attribute__((ext_vector_type(4)));
typedef short  bf16x8 __attribute__((ext_vector_type(8)));

#define NCHK 32
#define CLEN 64
#define SW   8      // scan window (double-buffered)

__device__ __forceinline__ ushort f2bf(float f) {
    uint u = __float_as_uint(f);
    u += 0x7FFF + ((u >> 16) & 1);          // RNE
    return (ushort)(u >> 16);
}
__device__ __forceinline__ float bf2f(ushort h) {
    return __uint_as_float((uint)h << 16);
}
__device__ __forceinline__ float softplus_f(float x) {
    return fmaxf(x, 0.f) + __logf(1.f + __expf(-fabsf(x)));
}
__device__ __forceinline__ float silu_f(float x) {
    return x / (1.f + __expf(-x));
}

// swizzled LDS chunk address (ushort units): row stride 32, chunk q
// permuted by row: c = (q + (row>>1)) & 3.
__device__ __forceinline__ int lds_addr(int row, int q) {
    return (row << 5) + ((((q + (row >> 1)) & 3)) << 3);
}
__device__ __forceinline__ int lds_frag_off(int lane) {
    const int r = lane & 15, q = lane >> 4;
    return (r << 5) + ((((q + (r >> 1)) & 3)) << 3);
}

__global__ __launch_bounds__(256)
void split_w_kernel(const float* __restrict__ src, ushort* __restrict__ hi,
                    ushort* __restrict__ lo)
{
    const int i = blockIdx.x * 256 + threadIdx.x;
    float4 v = ((const float4*)src)[i];
    ushort4 h, l;
    h.x = f2bf(v.x); l.x = f2bf(v.x - bf2f(h.x));
    h.y = f2bf(v.y); l.y = f2bf(v.y - bf2f(h.y));
    h.z = f2bf(v.z); l.z = f2bf(v.z - bf2f(h.z));
    h.w = f2bf(v.w); l.w = f2bf(v.w - bf2f(h.w));
    ((ushort4*)hi)[i] = h;
    ((ushort4*)lo)[i] = l;
}

__global__ __launch_bounds__(256)
void cvt_bf16_kernel(const float* __restrict__ src, ushort* __restrict__ dst)
{
    const int i = blockIdx.x * 256 + threadIdx.x;
    float4 v = ((const float4*)src)[i];
    ushort4 h;
    h.x = f2bf(v.x); h.y = f2bf(v.y); h.z = f2bf(v.z); h.w = f2bf(v.w);
    ((ushort4*)dst)[i] = h;
}

// C[M,N] = A[M,K](bf16) * B[N,K]^T(bf16), fp32 accumulate.
// 128x128 block, 4 waves x (4x4 of 16x16x32 MFMA). Swizzled LDS.
// EPI: 0 = fp32 store, 1 = softplus(v + bias[col]) fp32, 2 = bf16 store.
template <int EPI>
__global__ __launch_bounds__(256)
void gemm_mfma(const ushort* __restrict__ A, const ushort* __restrict__ Bm,
               const float* __restrict__ bias, void* __restrict__ Cout,
               int N, int K)
{
    __shared__ ushort As[4096];   // 8 KB
    __shared__ ushort Bs[4096];   // 8 KB

    const int tid  = threadIdx.x;
    const int lane = tid & 63;
    const int wave = tid >> 6;
    const int wm   = (wave >> 1) * 64;
    const int wn   = (wave & 1) * 64;
    const int row0 = blockIdx.y * 128;
    const int col0 = blockIdx.x * 128;

    const int crow = tid >> 2;            // 0..63
    const int cq   = tid & 3;             // 16B chunk
    const ushort* Ag0 = A  + (size_t)(row0 + crow) * K + cq * 8;
    const ushort* Ag1 = A  + (size_t)(row0 + crow + 64) * K + cq * 8;
    const ushort* Bg0 = Bm + (size_t)(col0 + crow) * K + cq * 8;
    const ushort* Bg1 = Bm + (size_t)(col0 + crow + 64) * K + cq * 8;
    const int st0 = lds_addr(crow, cq);
    const int st1 = st0 + 2048;

    const int flo = lds_frag_off(lane);
    const int fra = (wm << 5) + flo;
    const int frb = (wn << 5) + flo;

    f32x4 acc[4][4];
#pragma unroll
    for (int mi = 0; mi < 4; ++mi)
#pragma unroll
        for (int ni = 0; ni < 4; ++ni)
            acc[mi][ni] = (f32x4){0.f, 0.f, 0.f, 0.f};

    uint4 ra0 = *(const uint4*)Ag0, ra1 = *(const uint4*)Ag1;
    uint4 rb0 = *(const uint4*)Bg0, rb1 = *(const uint4*)Bg1;

    for (int k0 = 0; k0 < K; k0 += 32) {
        __syncthreads();
        *(uint4*)(As + st0) = ra0;
        *(uint4*)(As + st1) = ra1;
        *(uint4*)(Bs + st0) = rb0;
        *(uint4*)(Bs + st1) = rb1;
        __syncthreads();
        if (k0 + 32 < K) {
            ra0 = *(const uint4*)(Ag0 + k0 + 32);
            ra1 = *(const uint4*)(Ag1 + k0 + 32);
            rb0 = *(const uint4*)(Bg0 + k0 + 32);
            rb1 = *(const uint4*)(Bg1 + k0 + 32);
        }
        bf16x8 af[4], bf[4];
#pragma unroll
        for (int mi = 0; mi < 4; ++mi)
            af[mi] = *(const bf16x8*)(As + fra + mi * 512);
#pragma unroll
        for (int ni = 0; ni < 4; ++ni)
            bf[ni] = *(const bf16x8*)(Bs + frb + ni * 512);
#pragma unroll
        for (int mi = 0; mi < 4; ++mi)
#pragma unroll
            for (int ni = 0; ni < 4; ++ni)
                acc[mi][ni] = __builtin_amdgcn_mfma_f32_16x16x32_bf16(
                    af[mi], bf[ni], acc[mi][ni], 0, 0, 0);
    }

#pragma unroll
    for (int mi = 0; mi < 4; ++mi) {
        const int rg = row0 + wm + mi * 16 + (lane >> 4) * 4;
#pragma unroll
        for (int ni = 0; ni < 4; ++ni) {
            const int cg = col0 + wn + ni * 16 + (lane & 15);
            f32x4 v = acc[mi][ni];
            if (EPI == 1) {
                const float bv = bias[cg];
#pragma unroll
                for (int r = 0; r < 4; ++r) v[r] = softplus_f(v[r] + bv);
            }
#pragma unroll
            for (int r = 0; r < 4; ++r) {
                if (EPI == 2)
                    ((ushort*)Cout)[(size_t)(rg + r) * N + cg] = f2bf(v[r]);
                else
                    ((float*)Cout)[(size_t)(rg + r) * N + cg] = v[r];
            }
        }
    }
}

// Split-K bc GEMM: part[ks] = xc[:, ks*256:(ks+1)*256] @ Wx^T slice.
__global__ __launch_bounds__(256)
void gemm_bc_mfma(const ushort* __restrict__ A, const ushort* __restrict__ Bh,
                  const ushort* __restrict__ Bl, float* __restrict__ part)
{
    __shared__ ushort As[4096];
    __shared__ ushort Bhs[1024];
    __shared__ ushort Bls[1024];

    const int tid  = threadIdx.x;
    const int lane = tid & 63;
    const int wave = tid >> 6;
    const int ks   = blockIdx.x;     // 0..7
    const int mb   = blockIdx.y;     // 0..63
    const int row0 = mb * 128;
    const int kb   = ks * 256;

    const int crow = tid >> 2;
    const int cq   = tid & 3;
    const ushort* Ag0 = A + (size_t)(row0 + crow) * 2048 + kb + cq * 8;
    const ushort* Ag1 = A + (size_t)(row0 + crow + 64) * 2048 + kb + cq * 8;
    const int st0 = lds_addr(crow, cq);
    const int st1 = st0 + 2048;

    const int t2   = tid & 127;
    const int brow = t2 >> 2;        // 0..31
    const int bq   = t2 & 3;
    const ushort* Bg = (tid < 128 ? Bh : Bl) + (size_t)brow * 2048 + kb + bq * 8;
    ushort* Bdst     = (tid < 128 ? Bhs : Bls) + lds_addr(brow, bq);

    const int wm  = wave * 32;
    const int flo = lds_frag_off(lane);
    const int fra = (wm << 5) + flo;
    const int frb = flo;

    f32x4 acc[2][2];
#pragma unroll
    for (int mi = 0; mi < 2; ++mi)
#pragma unroll
        for (int ni = 0; ni < 2; ++ni)
            acc[mi][ni] = (f32x4){0.f, 0.f, 0.f, 0.f};

    uint4 ra0 = *(const uint4*)Ag0, ra1 = *(const uint4*)Ag1;
    uint4 rb  = *(const uint4*)Bg;

    for (int kt = 0; kt < 8; ++kt) {
        __syncthreads();
        *(uint4*)(As + st0) = ra0;
        *(uint4*)(As + st1) = ra1;
        *(uint4*)Bdst = rb;
        __syncthreads();
        if (kt < 7) {
            ra0 = *(const uint4*)(Ag0 + (kt + 1) * 32);
            ra1 = *(const uint4*)(Ag1 + (kt + 1) * 32);
            rb  = *(const uint4*)(Bg + (kt + 1) * 32);
        }
        bf16x8 af[2], bhf[2], blf[2];
#pragma unroll
        for (int mi = 0; mi < 2; ++mi)
            af[mi] = *(const bf16x8*)(As + fra + mi * 512);
#pragma unroll
        for (int ni = 0; ni < 2; ++ni) {
            bhf[ni] = *(const bf16x8*)(Bhs + frb + ni * 512);
            blf[ni] = *(const bf16x8*)(Bls + frb + ni * 512);
        }
#pragma unroll
        for (int mi = 0; mi < 2; ++mi)
#pragma unroll
            for (int ni = 0; ni < 2; ++ni) {
                acc[mi][ni] = __builtin_amdgcn_mfma_f32_16x16x32_bf16(
                    af[mi], bhf[ni], acc[mi][ni], 0, 0, 0);
                acc[mi][ni] = __builtin_amdgcn_mfma_f32_16x16x32_bf16(
                    af[mi], blf[ni], acc[mi][ni], 0, 0, 0);
            }
    }

#pragma unroll
    for (int mi = 0; mi < 2; ++mi) {
        const int rg = row0 + wm + mi * 16 + (lane >> 4) * 4;
#pragma unroll
        for (int ni = 0; ni < 2; ++ni) {
            const int cg = ni * 16 + (lane & 15);
            f32x4 v = acc[mi][ni];
#pragma unroll
            for (int r = 0; r < 4; ++r)
                part[((size_t)ks * 8192 + rg + r) * 32 + cg] = v[r];
        }
    }
}

__global__ __launch_bounds__(256)
void bc_reduce_kernel(const float* __restrict__ part, float* __restrict__ bc)
{
    const int i = blockIdx.x * 256 + threadIdx.x;   // 262144
    float s = 0.f;
#pragma unroll
    for (int ks = 0; ks < 8; ++ks)
        s += part[(size_t)ks * 262144 + i];
    bc[i] = s;
}

// Depthwise causal conv1d (4 taps) + bias + silu; bf16 in, bf16 out.
__global__ __launch_bounds__(256)
void conv_silu_kernel(const ushort* __restrict__ xi, const float* __restrict__ cw,
                      const float* __restrict__ cb, ushort* __restrict__ xc)
{
    const int idx = blockIdx.x * 256 + threadIdx.x;
    const int e   = (idx & 511) << 2;
    const int row = idx >> 9;
    const int l   = row & 2047;

    const float4 w0 = *(const float4*)(cw + (size_t)(e + 0) * 4);
    const float4 w1 = *(const float4*)(cw + (size_t)(e + 1) * 4);
    const float4 w2 = *(const float4*)(cw + (size_t)(e + 2) * 4);
    const float4 w3 = *(const float4*)(cw + (size_t)(e + 3) * 4);

    float4 acc = *(const float4*)(cb + e);

#define CONV_TAP(K_, WSEL)                                                  \
    {                                                                       \
        ushort4 t = *(const ushort4*)(xi + (size_t)(row - (K_)) * 2048 + e);\
        acc.x = fmaf(bf2f(t.x), w0.WSEL, acc.x);                            \
        acc.y = fmaf(bf2f(t.y), w1.WSEL, acc.y);                            \
        acc.z = fmaf(bf2f(t.z), w2.WSEL, acc.z);                            \
        acc.w = fmaf(bf2f(t.w), w3.WSEL, acc.w);                            \
    }
    if (l >= 3) CONV_TAP(3, x)
    if (l >= 2) CONV_TAP(2, y)
    if (l >= 1) CONV_TAP(1, z)
    CONV_TAP(0, w)
#undef CONV_TAP

    ushort4 o;
    o.x = f2bf(silu_f(acc.x)); o.y = f2bf(silu_f(acc.y));
    o.z = f2bf(silu_f(acc.z)); o.w = f2bf(silu_f(acc.w));
    *(ushort4*)(xc + (size_t)row * 2048 + e) = o;
}

// ---- d-parallel chunked selective scan (NCHK chunks of CLEN) ----

// Pass 1: chunks 0..NCHK-2, h from 0, writes he + P = exp(A * sum dt).
__global__ __launch_bounds__(256)
void scan_part1(const ushort* __restrict__ xcb, const float* __restrict__ dbuf,
                const float* __restrict__ bcbuf, const float* __restrict__ A_log,
                float* __restrict__ sum_h, float* __restrict__ sum_p)
{
    const int c    = blockIdx.x >> 5;          // 0..NCHK-2
    const int b    = (blockIdx.x >> 3) & 3;
    const int dblk = blockIdx.x & 7;
    const int d    = dblk * 256 + threadIdx.x;

    float Aval[16];
#pragma unroll
    for (int q = 0; q < 4; ++q) {
        float4 al = *(const float4*)(A_log + (size_t)d * 16 + q * 4);
        Aval[q*4+0] = -__expf(al.x); Aval[q*4+1] = -__expf(al.y);
        Aval[q*4+2] = -__expf(al.z); Aval[q*4+3] = -__expf(al.w);
    }

    const size_t row0 = (size_t)b * 2048 + (size_t)c * CLEN;
    const float*  dp  = dbuf + row0 * 2048 + d;
    const ushort* xp  = xcb  + row0 * 2048 + d;
    const float*  bcp = bcbuf + row0 * 32;

    float h[16];
#pragma unroll
    for (int s = 0; s < 16; ++s) h[s] = 0.f;
    float S = 0.f;

    float wdt[SW], wxv[SW];
#pragma unroll
    for (int j = 0; j < SW; ++j) {
        wdt[j] = dp[(size_t)j * 2048];
        wxv[j] = bf2f(xp[(size_t)j * 2048]);
    }
    float curB[16];
#pragma unroll
    for (int q = 0; q < 4; ++q)
        *(float4*)&curB[q*4] = *(const float4*)(bcp + q * 4);

    for (int l0 = 0; l0 < CLEN; l0 += SW) {
        float ndt[SW], nxv[SW];
        const bool more = (l0 + SW) < CLEN;
        if (more) {
#pragma unroll
            for (int j = 0; j < SW; ++j) {
                const size_t o = (size_t)(l0 + SW + j);
                ndt[j] = dp[o * 2048];
                nxv[j] = bf2f(xp[o * 2048]);
            }
        }
#pragma unroll
        for (int j = 0; j < SW; ++j) {
            const int l = l0 + j;
            float nB[16];
            if (l + 1 < CLEN) {
#pragma unroll
                for (int q = 0; q < 4; ++q)
                    *(float4*)&nB[q*4] = *(const float4*)(bcp + (size_t)(l+1) * 32 + q * 4);
            }
            const float dt = wdt[j];
            const float t  = dt * wxv[j];
            S += dt;
#pragma unroll
            for (int s = 0; s < 16; ++s)
                h[s] = __expf(dt * Aval[s]) * h[s] + curB[s] * t;
            if (l + 1 < CLEN) {
#pragma unroll
                for (int s = 0; s < 16; ++s) curB[s] = nB[s];
            }
        }
        if (more) {
#pragma unroll
            for (int j = 0; j < SW; ++j) { wdt[j] = ndt[j]; wxv[j] = nxv[j]; }
        }
    }

    float* sh = sum_h + ((((size_t)c * 4 + b) * 2048 + d) << 4);
    float* sp = sum_p + ((((size_t)c * 4 + b) * 2048 + d) << 4);
#pragma unroll
    for (int q = 0; q < 4; ++q) {
        *(float4*)(sh + q * 4) = make_float4(h[q*4], h[q*4+1], h[q*4+2], h[q*4+3]);
        *(float4*)(sp + q * 4) = make_float4(__expf(Aval[q*4] * S), __expf(Aval[q*4+1] * S),
                                             __expf(Aval[q*4+2] * S), __expf(Aval[q*4+3] * S));
    }
}

// Pass 2: all NCHK chunks; fold preceding summaries, scan, y bf16 out.
__global__ __launch_bounds__(256)
void scan_part2(const ushort* __restrict__ zbuf, const ushort* __restrict__ xcb,
                const float* __restrict__ dbuf, const float* __restrict__ bcbuf,
                const float* __restrict__ A_log, const float* __restrict__ Dp,
                const float* __restrict__ sum_h, const float* __restrict__ sum_p,
                ushort* __restrict__ ybuf)
{
    const int c    = blockIdx.x >> 5;          // 0..NCHK-1
    const int b    = (blockIdx.x >> 3) & 3;
    const int dblk = blockIdx.x & 7;
    const int d    = dblk * 256 + threadIdx.x;

    float Aval[16];
#pragma unroll
    for (int q = 0; q < 4; ++q) {
        float4 al = *(const float4*)(A_log + (size_t)d * 16 + q * 4);
        Aval[q*4+0] = -__expf(al.x); Aval[q*4+1] = -__expf(al.y);
        Aval[q*4+2] = -__expf(al.z); Aval[q*4+3] = -__expf(al.w);
    }
    const float Dv = Dp[d];

    float h[16];
#pragma unroll
    for (int s = 0; s < 16; ++s) h[s] = 0.f;
    for (int j = 0; j < c; ++j) {              // fold chunk summaries
        const float* sh = sum_h + ((((size_t)j * 4 + b) * 2048 + d) << 4);
        const float* sp = sum_p + ((((size_t)j * 4 + b) * 2048 + d) << 4);
#pragma unroll
        for (int q = 0; q < 4; ++q) {
            float4 vh = *(const float4*)(sh + q * 4);
            float4 vp = *(const float4*)(sp + q * 4);
            h[q*4+0] = vh.x + vp.x * h[q*4+0];
            h[q*4+1] = vh.y + vp.y * h[q*4+1];
            h[q*4+2] = vh.z + vp.z * h[q*4+2];
            h[q*4+3] = vh.w + vp.w * h[q*4+3];
        }
    }

    const size_t row0 = (size_t)b * 2048 + (size_t)c * CLEN;
    const float*  dp  = dbuf + row0 * 2048 + d;
    const ushort* xp  = xcb  + row0 * 2048 + d;
    const ushort* zp  = zbuf + row0 * 2048 + d;
    const float*  bcp = bcbuf + row0 * 32;
    ushort*       yp  = ybuf + row0 * 2048 + d;

    float wdt[SW], wxv[SW], wzv[SW];
#pragma unroll
    for (int j = 0; j < SW; ++j) {
        wdt[j] = dp[(size_t)j * 2048];
        wxv[j] = bf2f(xp[(size_t)j * 2048]);
        wzv[j] = bf2f(zp[(size_t)j * 2048]);
    }
    float curB[16], curC[16];
#pragma unroll
    for (int q = 0; q < 4; ++q) {
        *(float4*)&curB[q*4] = *(const float4*)(bcp + q * 4);
        *(float4*)&curC[q*4] = *(const float4*)(bcp + 16 + q * 4);
    }

    for (int l0 = 0; l0 < CLEN; l0 += SW) {
        float ndt[SW], nxv[SW], nzv[SW];
        const bool more = (l0 + SW) < CLEN;
        if (more) {
#pragma unroll
            for (int j = 0; j < SW; ++j) {
                const size_t o = (size_t)(l0 + SW + j);
                ndt[j] = dp[o * 2048];
                nxv[j] = bf2f(xp[o * 2048]);
                nzv[j] = bf2f(zp[o * 2048]);
            }
        }
#pragma unroll
        for (int j = 0; j < SW; ++j) {
            const int l = l0 + j;
            float nB[16], nC[16];
            if (l + 1 < CLEN) {
#pragma unroll
                for (int q = 0; q < 4; ++q) {
                    *(float4*)&nB[q*4] = *(const float4*)(bcp + (size_t)(l+1) * 32 + q * 4);
                    *(float4*)&nC[q*4] = *(const float4*)(bcp + (size_t)(l+1) * 32 + 16 + q * 4);
                }
            }
            const float dt = wdt[j];
            const float t  = dt * wxv[j];
#pragma unroll
            for (int s = 0; s < 16; ++s)
                h[s] = __expf(dt * Aval[s]) * h[s] + curB[s] * t;
            float y0 = 0.f, y1 = 0.f, y2 = 0.f, y3 = 0.f;
#pragma unroll
            for (int s = 0; s < 16; s += 4) {
                y0 = fmaf(h[s+0], curC[s+0], y0);
                y1 = fmaf(h[s+1], curC[s+1], y1);
                y2 = fmaf(h[s+2], curC[s+2], y2);
                y3 = fmaf(h[s+3], curC[s+3], y3);
            }
            float y = (y0 + y1) + (y2 + y3) + Dv * wxv[j];
            yp[(size_t)l * 2048] = f2bf(y * silu_f(wzv[j]));
            if (l + 1 < CLEN) {
#pragma unroll
                for (int s = 0; s < 16; ++s) { curB[s] = nB[s]; curC[s] = nC[s]; }
            }
        }
        if (more) {
#pragma unroll
            for (int j = 0; j < SW; ++j) {
                wdt[j] = ndt[j]; wxv[j] = nxv[j]; wzv[j] = nzv[j];
            }
        }
    }
}

extern "C" void kernel_launch(void* const* d_in, const int* in_sizes, int n_in,
                              void* d_out, int out_size, void* d_ws, size_t ws_size,
                              hipStream_t stream)
{
    const float* x          = (const float*)d_in[0];
    const float* in_proj_w  = (const float*)d_in[1];
    const float* conv_w     = (const float*)d_in[2];
    const float* conv_b     = (const float*)d_in[3];
    const float* x_proj_w   = (const float*)d_in[4];
    const float* dt_proj_w  = (const float*)d_in[5];
    const float* dt_proj_b  = (const float*)d_in[6];
    const float* A_log      = (const float*)d_in[7];
    const float* Dp         = (const float*)d_in[8];
    const float* out_proj_w = (const float*)d_in[9];
    float* out = (float*)d_out;

    // Workspace (~232 MB of 256 MiB)
    ushort* XI    = (ushort*)d_ws;                    // 32 MB; later Y'
    ushort* Z     = XI + 16777216;                    // 32 MB
    ushort* XC2   = Z + 16777216;                     // 32 MB
    float*  DELTA = (float*)(XC2 + 16777216);         // 64 MB
    ushort* XP    = (ushort*)DELTA;                   // x' bf16 (pre-DELTA)
    ushort* WINH  = (ushort*)(DELTA + 16777216);      // 8 MB [4096,1024] bf16
    ushort* WDTH  = WINH + 4194304;                   // 8 MB [2048,2048] bf16
    ushort* WOUTH = WDTH + 4194304;                   // 4 MB [1024,2048] bf16
    float*  BC    = (float*)(WOUTH + 2097152);        // 1 MB
    float*  SUMH  = BC + 262144;                      // 16.8 MB (32*4*2048*16)
    float*  SUMP  = SUMH + 4194304;                   // 16.8 MB
    ushort* XPH   = (ushort*)(SUMP + 4194304);        // 128 KB (x_proj hi)
    ushort* XPL   = XPH + 65536;                      // 128 KB
    float*  PART  = (float*)(XPL + 65536);            // 8 MB split-K partials
    ushort* Yp    = XI;

    const dim3 blk(256);

    // 0) conversions (weights plain bf16 except x_proj hi/lo)
    cvt_bf16_kernel<<<dim3(8192), blk, 0, stream>>>(x, XP);
    cvt_bf16_kernel<<<dim3(4096), blk, 0, stream>>>(in_proj_w, WINH);
    cvt_bf16_kernel<<<dim3(4096), blk, 0, stream>>>(dt_proj_w, WDTH);
    cvt_bf16_kernel<<<dim3(2048), blk, 0, stream>>>(out_proj_w, WOUTH);
    split_w_kernel<<<dim3(64),    blk, 0, stream>>>(x_proj_w, XPH, XPL);

    // 1) xi, z
    gemm_mfma<2><<<dim3(16, 64), blk, 0, stream>>>(XP, WINH, nullptr, XI, 2048, 1024);
    gemm_mfma<2><<<dim3(16, 64), blk, 0, stream>>>(XP, WINH + 2097152, nullptr, Z, 2048, 1024);

    // 2) xc = silu(conv(xi) + b)
    conv_silu_kernel<<<dim3(16384), blk, 0, stream>>>(XI, conv_w, conv_b, XC2);

    // 3) delta = softplus(xc @ Wdt^T + b)
    gemm_mfma<1><<<dim3(16, 64), blk, 0, stream>>>(XC2, WDTH, dt_proj_b, DELTA, 2048, 2048);

    // 4) bc = xc @ x_proj_w^T  (split-K MFMA + reduce)
    gemm_bc_mfma<<<dim3(8, 64), blk, 0, stream>>>(XC2, XPH, XPL, PART);
    bc_reduce_kernel<<<dim3(1024), blk, 0, stream>>>(PART, BC);

    // 5) chunked scan: pass1 (chunks 0..NCHK-2) then pass2 (all NCHK)
    scan_part1<<<dim3((NCHK - 1) * 32), blk, 0, stream>>>(XC2, DELTA, BC, A_log, SUMH, SUMP);
    scan_part2<<<dim3(NCHK * 32), blk, 0, stream>>>(Z, XC2, DELTA, BC, A_log, Dp,
                                                    SUMH, SUMP, Yp);

    // 6) out = y @ Wout^T
    gemm_mfma<0><<<dim3(8, 64), blk, 0, stream>>>(Yp, WOUTH, nullptr, out, 1024, 2048);
}